// Round 1
// baseline (425.226 us; speedup 1.0000x reference)
//
#include <hip/hip_runtime.h>
#include <math.h>

// ---------------- problem constants ----------------
#define NRES 64
#define NXY  4096      // 64*64
#define NVOL 262144    // 64^3
#define BB   16
#define WID  32
#define MM   12
#define R24  24

constexpr double DX_d   = 2.0 * 3.14159265358979323846 / 64.0;
constexpr float  INV2DX = (float)(1.0 / (2.0 * DX_d));
constexpr float  INVDX2 = (float)(1.0 / (DX_d * DX_d));
constexpr float  DT_c   = 0.001f;
constexpr float  NU_c   = 0.002f;

// ---------------- workspace layout (float offsets) ----------------
constexpr size_t OFF_FR  = 0;                                  // 24*64 fwd row twiddles (e^{-i})
constexpr size_t OFF_FI  = OFF_FR + (size_t)R24 * NRES;
constexpr size_t OFF_GR  = OFF_FI + (size_t)R24 * NRES;        // 12*64 col twiddles (e^{-i})
constexpr size_t OFF_GI  = OFF_GR + (size_t)MM * NRES;
constexpr size_t OFF_CL  = OFF_GI + (size_t)MM * NRES;         // closure_in (B,10,64,64)
constexpr size_t OFF_HA  = OFF_CL + (size_t)BB * 10 * NXY;     // h buffer A (B,32,64,64)
constexpr size_t OFF_HB  = OFF_HA + (size_t)BB * WID * NXY;    // h buffer B
constexpr size_t OFF_T1R = OFF_HB + (size_t)BB * WID * NXY;    // (B,32,24,64)
constexpr size_t OFF_T1I = OFF_T1R + (size_t)BB * WID * R24 * NRES;
constexpr size_t OFF_XR  = OFF_T1I + (size_t)BB * WID * R24 * NRES;  // (B,32,24,12)
constexpr size_t OFF_XI  = OFF_XR + (size_t)BB * WID * R24 * MM;
constexpr size_t OFF_MR  = OFF_XI + (size_t)BB * WID * R24 * MM;
constexpr size_t OFF_MI  = OFF_MR + (size_t)BB * WID * R24 * MM;
constexpr size_t OFF_AR  = OFF_MI + (size_t)BB * WID * R24 * MM;     // (B,32,12,64)
constexpr size_t OFF_AI  = OFF_AR + (size_t)BB * WID * MM * NRES;
constexpr size_t OFF_H1  = OFF_AI + (size_t)BB * WID * MM * NRES;    // (B,128,64,64)
constexpr size_t OFF_TAU = OFF_H1 + (size_t)BB * 128 * NXY;          // (B,6,64,64)

__device__ __forceinline__ float gelu_tanh(float x) {
    float x3 = x * x * x;
    float t  = tanhf(0.79788456080286535588f * (x + 0.044715f * x3));
    return 0.5f * x * (1.0f + t);
}

// ---------------- K0: twiddle tables ----------------
__global__ void k_twiddle(float* __restrict__ ws) {
    int idx = blockIdx.x * 256 + threadIdx.x;
    if (idx < R24 * NRES) {
        int r = idx / NRES, x = idx % NRES;
        int kx = (r < MM) ? r : (r + 40);   // rows 0..11 and 52..63
        double ang = -2.0 * 3.14159265358979323846 * (double)(kx * x) / 64.0;
        ws[OFF_FR + idx] = (float)cos(ang);
        ws[OFF_FI + idx] = (float)sin(ang);
    }
    if (idx < MM * NRES) {
        int ky = idx / NRES, y = idx % NRES;
        double ang = -2.0 * 3.14159265358979323846 * (double)(ky * y) / 64.0;
        ws[OFF_GR + idx] = (float)cos(ang);
        ws[OFF_GI + idx] = (float)sin(ang);
    }
}

// ---------------- K1: closure input (B,10,64,64) from mid-plane gradients ----------------
__global__ void k_closure(const float* __restrict__ v, float* __restrict__ ws) {
    int idx = blockIdx.x * 256 + threadIdx.x;   // 65536 = B*4096
    int b = idx >> 12, p = idx & 4095;
    int x = p >> 6, z = p & 63;
    int xp = (x + 1) & 63, xm = (x - 1) & 63;
    float g[3][3];
    for (int i = 0; i < 3; i++) {
        const float* vb = v + (((size_t)(b * 3 + i)) << 18);
        float u   = vb[(size_t)x  * 4096 + 32 * 64 + z];
        float uxp = vb[(size_t)xp * 4096 + 32 * 64 + z];
        float uxm = vb[(size_t)xm * 4096 + 32 * 64 + z];
        float uyp = vb[(size_t)x  * 4096 + 33 * 64 + z];
        float uym = vb[(size_t)x  * 4096 + 31 * 64 + z];
        g[i][0] = (uxp - uxm) * INV2DX;
        g[i][1] = (uyp - uym) * INV2DX;
        g[i][2] = 0.1f * u;
    }
    float ss = 0.0f;
    for (int i = 0; i < 3; i++)
        for (int j = 0; j < 3; j++) {
            float s = 0.5f * (g[i][j] + g[j][i]);
            ss += s * s;
        }
    float smag = sqrtf(2.0f * ss);
    float* cl = ws + OFF_CL + (size_t)b * 10 * NXY;
    for (int i = 0; i < 3; i++)
        for (int j = 0; j < 3; j++)
            cl[(size_t)(i * 3 + j) * NXY + p] = g[i][j];
    cl[(size_t)9 * NXY + p] = smag;
}

// ---------------- K2: fc0 lift 10 -> 32 ----------------
__global__ void k_fc0(const float* __restrict__ cl, const float* __restrict__ w,
                      const float* __restrict__ bias, float* __restrict__ h) {
    int idx = blockIdx.x * 256 + threadIdx.x;   // B*32*4096
    int p = idx & 4095;
    int bd = idx >> 12;
    int d = bd & 31, b = bd >> 5;
    const float* c0 = cl + (size_t)b * 10 * NXY;
    float acc = bias[d];
#pragma unroll
    for (int c = 0; c < 10; c++) acc += c0[(size_t)c * NXY + p] * w[c * 32 + d];
    h[(size_t)bd * NXY + p] = acc;
}

// ---------------- K3: forward DFT over x (rows), 24 truncated modes ----------------
__global__ void k_fwd1(const float* __restrict__ h, const float* __restrict__ ws,
                       float* __restrict__ t1r, float* __restrict__ t1i) {
    int idx = blockIdx.x * 256 + threadIdx.x;   // B*32*24*64
    int y = idx & 63;
    int t = idx >> 6;          // bc*24 + r
    int r = t % 24;
    int bc = t / 24;
    const float* Fr = ws + OFF_FR + (size_t)r * 64;
    const float* Fi = ws + OFF_FI + (size_t)r * 64;
    const float* hp = h + (size_t)bc * NXY + y;
    float ar = 0.f, ai = 0.f;
#pragma unroll 16
    for (int x = 0; x < 64; x++) {
        float hv = hp[(size_t)x * 64];
        ar += hv * Fr[x];
        ai += hv * Fi[x];
    }
    t1r[idx] = ar; t1i[idx] = ai;
}

// ---------------- K4: forward DFT over y (cols), 12 modes ----------------
__global__ void k_fwd2(const float* __restrict__ t1r, const float* __restrict__ t1i,
                       const float* __restrict__ ws, float* __restrict__ xr, float* __restrict__ xi) {
    int idx = blockIdx.x * 256 + threadIdx.x;   // B*32*24*12
    int ky = idx % 12;
    int t  = idx / 12;
    const float* Gr = ws + OFF_GR + (size_t)ky * 64;
    const float* Gi = ws + OFF_GI + (size_t)ky * 64;
    const float* tr = t1r + (size_t)t * 64;
    const float* ti = t1i + (size_t)t * 64;
    float ar = 0.f, ai = 0.f;
#pragma unroll 16
    for (int y = 0; y < 64; y++) {
        float a = tr[y], b = ti[y], c = Gr[y], d = Gi[y];
        ar += a * c - b * d;
        ai += a * d + b * c;
    }
    xr[idx] = ar; xi[idx] = ai;
}

// ---------------- K5: per-mode complex channel mix (the spectral einsum) ----------------
__global__ void k_spec(const float* __restrict__ xr, const float* __restrict__ xi,
                       const float* __restrict__ w1, const float* __restrict__ w2,
                       float* __restrict__ mr, float* __restrict__ mi) {
    int idx = blockIdx.x * 256 + threadIdx.x;   // B*32*24*12 ; layout (b*32+o)*288 + r*12 + ky
    int ky = idx % 12;
    int t  = idx / 12;
    int r  = t % 24;
    int bo = t / 24;
    int o = bo & 31, b = bo >> 5;
    int kx = (r < 12) ? r : (r - 12);
    const float* wl = (r < 12) ? w1 : w2;       // already offset to layer l
    int kxy = kx * 12 + ky;
    float ar = 0.f, ai = 0.f;
    for (int i = 0; i < 32; i++) {
        size_t xoff = ((size_t)(b * 32 + i) * 24 + r) * 12 + ky;
        float a = xr[xoff], bi_ = xi[xoff];
        const float* wp = wl + ((size_t)(i * 32 + o) * 144 + kxy) * 2;
        float wr_ = wp[0], wi_ = wp[1];
        ar += a * wr_ - bi_ * wi_;
        ai += a * wi_ + bi_ * wr_;
    }
    mr[idx] = ar; mi[idx] = ai;
}

// ---------------- K6: inverse DFT over kx rows -> A(b,o,ky,x) ----------------
__global__ void k_inv1(const float* __restrict__ mr, const float* __restrict__ mi,
                       const float* __restrict__ ws, float* __restrict__ Ar, float* __restrict__ Ai) {
    int idx = blockIdx.x * 256 + threadIdx.x;   // B*32*12*64 ; (bo*12+ky)*64 + x
    int x = idx & 63;
    int t = idx >> 6;
    int ky = t % 12;
    int bo = t / 12;
    float ar = 0.f, ai = 0.f;
    for (int r = 0; r < 24; r++) {
        size_t moff = ((size_t)bo * 24 + r) * 12 + ky;
        float a = mr[moff], b = mi[moff];
        float c = ws[OFF_FR + (size_t)r * 64 + x];   // cos(theta)
        float d = ws[OFF_FI + (size_t)r * 64 + x];   // -sin(theta)
        // multiply by e^{+i theta} = (c, -d)
        ar += a * c + b * d;
        ai += b * c - a * d;
    }
    Ar[idx] = ar; Ai[idx] = ai;
}

// ---------------- K7: inverse DFT over ky (c2r semantics) + 1x1 conv + gelu ----------------
template <int DOGELU>
__global__ void k_inv2conv(const float* __restrict__ Ar, const float* __restrict__ Ai,
                           const float* __restrict__ hin, const float* __restrict__ cw,
                           const float* __restrict__ cb, const float* __restrict__ ws,
                           float* __restrict__ hout) {
    int idx = blockIdx.x * 256 + threadIdx.x;   // B*32*4096
    int p = idx & 4095;
    int y = p & 63, x = p >> 6;
    int bo = idx >> 12;
    int o = bo & 31, b = bo >> 5;
    const float* ArP = Ar + (size_t)bo * 12 * 64;
    const float* AiP = Ai + (size_t)bo * 12 * 64;
    float s = ArP[x];                            // ky=0 : only real part of DC column survives c2r
#pragma unroll
    for (int ky = 1; ky < 12; ky++) {
        float gr = ws[OFF_GR + (size_t)ky * 64 + y];
        float gi = ws[OFF_GI + (size_t)ky * 64 + y];
        // Re(A * e^{+i theta}) = Ar*cos - Ai*sin = Ar*gr + Ai*gi
        s += 2.0f * (ArP[(size_t)ky * 64 + x] * gr + AiP[(size_t)ky * 64 + x] * gi);
    }
    s *= (1.0f / 4096.0f);
    const float* hp = hin + (size_t)b * WID * NXY + p;
    float acc = cb[o];
#pragma unroll
    for (int c = 0; c < 32; c++) acc += hp[(size_t)c * NXY] * cw[c * 32 + o];
    float val = s + acc;
    if (DOGELU) val = gelu_tanh(val);
    hout[(size_t)bo * NXY + p] = val;
}

// ---------------- K8: fc1 (32 -> 128) + gelu ----------------
__global__ void k_fc1(const float* __restrict__ h, const float* __restrict__ w,
                      const float* __restrict__ bias, float* __restrict__ out) {
    int idx = blockIdx.x * 256 + threadIdx.x;   // B*128*4096
    int p = idx & 4095;
    int be = idx >> 12;
    int e = be & 127, b = be >> 7;
    const float* hp = h + (size_t)b * WID * NXY + p;
    float acc = bias[e];
#pragma unroll
    for (int c = 0; c < 32; c++) acc += hp[(size_t)c * NXY] * w[c * 128 + e];
    out[(size_t)be * NXY + p] = gelu_tanh(acc);
}

// ---------------- K9: fc2 (128 -> 6) ----------------
__global__ void k_fc2(const float* __restrict__ h1, const float* __restrict__ w,
                      const float* __restrict__ bias, float* __restrict__ tau) {
    int idx = blockIdx.x * 256 + threadIdx.x;   // B*6*4096
    int p = idx & 4095;
    int bt = idx >> 12;
    int t = bt % 6, b = bt / 6;
    const float* hp = h1 + (size_t)b * 128 * NXY + p;
    float acc = bias[t];
#pragma unroll 16
    for (int e = 0; e < 128; e++) acc += hp[(size_t)e * NXY] * w[e * 6 + t];
    tau[(size_t)bt * NXY + p] = acc;
}

// ---------------- K10: NS update ----------------
__global__ void k_ns(const float* __restrict__ v, const float* __restrict__ tau,
                     float* __restrict__ out) {
    int idx = blockIdx.x * 256 + threadIdx.x;   // B*64^3
    int b = idx >> 18;
    int srem = idx & (NVOL - 1);
    int x = srem >> 12, y = (srem >> 6) & 63, z = srem & 63;
    int xp = (x + 1) & 63, xm = (x - 1) & 63;
    int yp = (y + 1) & 63, ym = (y - 1) & 63;
    int zp = (z + 1) & 63, zm = (z - 1) & 63;
    float u[3], gx[3], gy[3], gz[3], lap[3];
    for (int i = 0; i < 3; i++) {
        const float* vb = v + (((size_t)(b * 3 + i)) << 18);
        float c   = vb[(size_t)x  * 4096 + y  * 64 + z];
        float axp = vb[(size_t)xp * 4096 + y  * 64 + z];
        float axm = vb[(size_t)xm * 4096 + y  * 64 + z];
        float ayp = vb[(size_t)x  * 4096 + yp * 64 + z];
        float aym = vb[(size_t)x  * 4096 + ym * 64 + z];
        float azp = vb[(size_t)x  * 4096 + y  * 64 + zp];
        float azm = vb[(size_t)x  * 4096 + y  * 64 + zm];
        u[i] = c;
        gx[i] = (axp - axm) * INV2DX;
        gy[i] = (ayp - aym) * INV2DX;
        gz[i] = (azp - azm) * INV2DX;
        lap[i] = (axp + axm + ayp + aym + azp + azm - 6.0f * c) * INVDX2;
    }
    const float* tb = tau + (size_t)b * 6 * NXY;
    int pxp = xp * 64 + y, pxm = xm * 64 + y, pyp = x * 64 + yp, pym = x * 64 + ym;
    float d0 = (tb[0 * NXY + pxp] - tb[0 * NXY + pxm]) * INV2DX +
               (tb[3 * NXY + pyp] - tb[3 * NXY + pym]) * INV2DX;
    float d1 = (tb[3 * NXY + pxp] - tb[3 * NXY + pxm]) * INV2DX +
               (tb[1 * NXY + pyp] - tb[1 * NXY + pym]) * INV2DX;
    float d2 = (tb[4 * NXY + pxp] - tb[4 * NXY + pxm]) * INV2DX +
               (tb[5 * NXY + pyp] - tb[5 * NXY + pym]) * INV2DX;
    float conv0 = u[0] * gx[0] + u[1] * gx[1] + u[2] * gx[2];
    float conv1 = u[0] * gy[0] + u[1] * gy[1] + u[2] * gy[2];
    float conv2 = u[0] * gz[0] + u[1] * gz[1] + u[2] * gz[2];
    size_t so = ((size_t)b * 3) * NVOL + (size_t)srem;
    out[so]            = u[0] + DT_c * (-conv0 + NU_c * lap[0] + d0);
    out[so + NVOL]     = u[1] + DT_c * (-conv1 + NU_c * lap[1] + d1);
    out[so + 2 * NVOL] = u[2] + DT_c * (-conv2 + NU_c * lap[2] + d2);
}

extern "C" void kernel_launch(void* const* d_in, const int* in_sizes, int n_in,
                              void* d_out, int out_size, void* d_ws, size_t ws_size,
                              hipStream_t stream) {
    const float* vel   = (const float*)d_in[0];
    const float* fc0w  = (const float*)d_in[1];
    const float* fc0b  = (const float*)d_in[2];
    const float* sw1   = (const float*)d_in[3];
    const float* sw2   = (const float*)d_in[4];
    const float* convw = (const float*)d_in[5];
    const float* convb = (const float*)d_in[6];
    const float* fc1w  = (const float*)d_in[7];
    const float* fc1b  = (const float*)d_in[8];
    const float* fc2w  = (const float*)d_in[9];
    const float* fc2b  = (const float*)d_in[10];
    float* ws  = (float*)d_ws;
    float* out = (float*)d_out;

    k_twiddle<<<6, 256, 0, stream>>>(ws);
    k_closure<<<256, 256, 0, stream>>>(vel, ws);
    k_fc0<<<8192, 256, 0, stream>>>(ws + OFF_CL, fc0w, fc0b, ws + OFF_HA);

    float* hcur  = ws + OFF_HA;
    float* hnext = ws + OFF_HB;
    for (int l = 0; l < 4; l++) {
        const float* wl1 = sw1 + (size_t)l * WID * WID * MM * MM * 2;
        const float* wl2 = sw2 + (size_t)l * WID * WID * MM * MM * 2;
        const float* cwl = convw + (size_t)l * WID * WID;
        const float* cbl = convb + (size_t)l * WID;
        k_fwd1<<<3072, 256, 0, stream>>>(hcur, ws, ws + OFF_T1R, ws + OFF_T1I);
        k_fwd2<<<576, 256, 0, stream>>>(ws + OFF_T1R, ws + OFF_T1I, ws, ws + OFF_XR, ws + OFF_XI);
        k_spec<<<576, 256, 0, stream>>>(ws + OFF_XR, ws + OFF_XI, wl1, wl2, ws + OFF_MR, ws + OFF_MI);
        k_inv1<<<1536, 256, 0, stream>>>(ws + OFF_MR, ws + OFF_MI, ws, ws + OFF_AR, ws + OFF_AI);
        if (l < 3)
            k_inv2conv<1><<<8192, 256, 0, stream>>>(ws + OFF_AR, ws + OFF_AI, hcur, cwl, cbl, ws, hnext);
        else
            k_inv2conv<0><<<8192, 256, 0, stream>>>(ws + OFF_AR, ws + OFF_AI, hcur, cwl, cbl, ws, hnext);
        float* tmp = hcur; hcur = hnext; hnext = tmp;
    }

    k_fc1<<<32768, 256, 0, stream>>>(hcur, fc1w, fc1b, ws + OFF_H1);
    k_fc2<<<1536, 256, 0, stream>>>(ws + OFF_H1, fc2w, fc2b, ws + OFF_TAU);
    k_ns<<<16384, 256, 0, stream>>>(vel, ws + OFF_TAU, out);
}

// Round 2
// 419.852 us; speedup vs baseline: 1.0128x; 1.0128x over previous
//
#include <hip/hip_runtime.h>
#include <math.h>

// ---------------- problem constants ----------------
#define NRES 64
#define NXY  4096      // 64*64
#define NVOL 262144    // 64^3
#define BB   16
#define WID  32
#define MM   12
#define R24  24

constexpr double DX_d   = 2.0 * 3.14159265358979323846 / 64.0;
constexpr float  INV2DX = (float)(1.0 / (2.0 * DX_d));
constexpr float  INVDX2 = (float)(1.0 / (DX_d * DX_d));
constexpr float  DT_c   = 0.001f;
constexpr float  NU_c   = 0.002f;

// ---------------- workspace layout (float offsets) ----------------
constexpr size_t OFF_FR  = 0;                                  // 24*64 fwd row twiddles (e^{-i})
constexpr size_t OFF_FI  = OFF_FR + (size_t)R24 * NRES;
constexpr size_t OFF_GR  = OFF_FI + (size_t)R24 * NRES;        // 12*64 col twiddles (e^{-i})
constexpr size_t OFF_GI  = OFF_GR + (size_t)MM * NRES;
constexpr size_t OFF_CL  = OFF_GI + (size_t)MM * NRES;         // closure_in (B,10,64,64)
constexpr size_t OFF_HA  = OFF_CL + (size_t)BB * 10 * NXY;     // h buffer A (B,32,64,64)
constexpr size_t OFF_HB  = OFF_HA + (size_t)BB * WID * NXY;    // h buffer B
constexpr size_t OFF_T1R = OFF_HB + (size_t)BB * WID * NXY;    // (B,32,24,64)
constexpr size_t OFF_T1I = OFF_T1R + (size_t)BB * WID * R24 * NRES;
constexpr size_t OFF_XR  = OFF_T1I + (size_t)BB * WID * R24 * NRES;  // (B,32,24,12)
constexpr size_t OFF_XI  = OFF_XR + (size_t)BB * WID * R24 * MM;
constexpr size_t OFF_MR  = OFF_XI + (size_t)BB * WID * R24 * MM;
constexpr size_t OFF_MI  = OFF_MR + (size_t)BB * WID * R24 * MM;
constexpr size_t OFF_AR  = OFF_MI + (size_t)BB * WID * R24 * MM;     // (B,32,12,64)
constexpr size_t OFF_AI  = OFF_AR + (size_t)BB * WID * MM * NRES;
constexpr size_t OFF_H1  = OFF_AI + (size_t)BB * WID * MM * NRES;    // region reused below
constexpr size_t OFF_TAU = OFF_H1 + (size_t)BB * 128 * NXY;          // (B,6,64,64)

// reuse the (now unneeded) H1 region: spectral image + transposed weights
constexpr size_t OFF_SP  = OFF_H1;                                   // (B,32,64,64) = 2.1M floats
constexpr size_t OFF_W1T = OFF_H1 + (size_t)BB * WID * NXY;          // 128x32
constexpr size_t OFF_CWT = OFF_W1T + 4096;                           // 4 layers x 32o x 32c
constexpr size_t OFF_W0T = OFF_CWT + 4096;                           // 32d x 10c

__device__ __forceinline__ float gelu_fast(float x) {
    float z = 0.79788456080286535588f * (x + 0.044715f * x * x * x);
    float e = __expf(2.0f * z);
    float t = 1.0f - 2.0f / (e + 1.0f);
    return 0.5f * x * (1.0f + t);
}

// ---------------- K0: twiddle tables ----------------
__global__ void k_twiddle(float* __restrict__ ws) {
    int idx = blockIdx.x * 256 + threadIdx.x;
    if (idx < R24 * NRES) {
        int r = idx / NRES, x = idx % NRES;
        int kx = (r < MM) ? r : (r + 40);   // rows 0..11 and 52..63
        double ang = -2.0 * 3.14159265358979323846 * (double)(kx * x) / 64.0;
        ws[OFF_FR + idx] = (float)cos(ang);
        ws[OFF_FI + idx] = (float)sin(ang);
    }
    if (idx < MM * NRES) {
        int ky = idx / NRES, y = idx % NRES;
        double ang = -2.0 * 3.14159265358979323846 * (double)(ky * y) / 64.0;
        ws[OFF_GR + idx] = (float)cos(ang);
        ws[OFF_GI + idx] = (float)sin(ang);
    }
}

// ---------------- K0b: transpose weights so per-output rows are contiguous (enables s_load) ----
__global__ void k_prep(const float* __restrict__ fc1w, const float* __restrict__ convw,
                       const float* __restrict__ fc0w, float* __restrict__ ws) {
    int i = blockIdx.x * 256 + threadIdx.x;
    if (i < 4096) {                       // fc1_w (32,128) -> W1T[e][c]
        int c = i >> 7, e = i & 127;
        ws[OFF_W1T + (size_t)e * 32 + c] = fc1w[i];
    } else if (i < 8192) {                // conv_w (4,32,32) -> CWT[l][o][c]
        int j = i - 4096;
        int l = j >> 10, r = j & 1023;
        int c = r >> 5, o = r & 31;
        ws[OFF_CWT + (size_t)l * 1024 + o * 32 + c] = convw[j];
    } else if (i < 8512) {                // fc0_w (10,32) -> W0T[d][c]
        int j = i - 8192;
        int c = j >> 5, d = j & 31;
        ws[OFF_W0T + (size_t)d * 10 + c] = fc0w[j];
    }
}

// ---------------- K1: closure input (B,10,64,64) from mid-plane gradients ----------------
__global__ void k_closure(const float* __restrict__ v, float* __restrict__ ws) {
    int idx = blockIdx.x * 256 + threadIdx.x;   // 65536 = B*4096
    int b = idx >> 12, p = idx & 4095;
    int x = p >> 6, z = p & 63;
    int xp = (x + 1) & 63, xm = (x - 1) & 63;
    float g[3][3];
    for (int i = 0; i < 3; i++) {
        const float* vb = v + (((size_t)(b * 3 + i)) << 18);
        float u   = vb[(size_t)x  * 4096 + 32 * 64 + z];
        float uxp = vb[(size_t)xp * 4096 + 32 * 64 + z];
        float uxm = vb[(size_t)xm * 4096 + 32 * 64 + z];
        float uyp = vb[(size_t)x  * 4096 + 33 * 64 + z];
        float uym = vb[(size_t)x  * 4096 + 31 * 64 + z];
        g[i][0] = (uxp - uxm) * INV2DX;
        g[i][1] = (uyp - uym) * INV2DX;
        g[i][2] = 0.1f * u;
    }
    float ss = 0.0f;
    for (int i = 0; i < 3; i++)
        for (int j = 0; j < 3; j++) {
            float s = 0.5f * (g[i][j] + g[j][i]);
            ss += s * s;
        }
    float smag = sqrtf(2.0f * ss);
    float* cl = ws + OFF_CL + (size_t)b * 10 * NXY;
    for (int i = 0; i < 3; i++)
        for (int j = 0; j < 3; j++)
            cl[(size_t)(i * 3 + j) * NXY + p] = g[i][j];
    cl[(size_t)9 * NXY + p] = smag;
}

// ---------------- K2: fc0 lift 10 -> 32 (per-pixel thread, scalar weights) ----------------
__global__ void k_fc0(const float* __restrict__ cl, const float* __restrict__ w0t,
                      const float* __restrict__ bias, float* __restrict__ h) {
    int pix = blockIdx.x * 256 + threadIdx.x;   // 65536
    int b = pix >> 12, p = pix & 4095;
    const float* c0 = cl + (size_t)b * 10 * NXY + p;
    float cv[10];
#pragma unroll
    for (int c = 0; c < 10; c++) cv[c] = c0[(size_t)c * NXY];
    float* hp = h + (size_t)b * WID * NXY + p;
    for (int d = 0; d < 32; d++) {
        float acc = bias[d];
        const float* wr = w0t + (size_t)d * 10;
#pragma unroll
        for (int c = 0; c < 10; c++) acc += cv[c] * wr[c];
        hp[(size_t)d * NXY] = acc;
    }
}

// ---------------- K3: forward DFT over x (rows), 24 truncated modes ----------------
__global__ void k_fwd1(const float* __restrict__ h, const float* __restrict__ ws,
                       float* __restrict__ t1r, float* __restrict__ t1i) {
    int idx = blockIdx.x * 256 + threadIdx.x;   // B*32*24*64
    int y = idx & 63;
    int t = idx >> 6;          // bc*24 + r
    int r = t % 24;
    int bc = t / 24;
    const float* Fr = ws + OFF_FR + (size_t)r * 64;
    const float* Fi = ws + OFF_FI + (size_t)r * 64;
    const float* hp = h + (size_t)bc * NXY + y;
    float ar = 0.f, ai = 0.f;
#pragma unroll 16
    for (int x = 0; x < 64; x++) {
        float hv = hp[(size_t)x * 64];
        ar += hv * Fr[x];
        ai += hv * Fi[x];
    }
    t1r[idx] = ar; t1i[idx] = ai;
}

// ---------------- K4: forward DFT over y (cols), 12 modes ----------------
__global__ void k_fwd2(const float* __restrict__ t1r, const float* __restrict__ t1i,
                       const float* __restrict__ ws, float* __restrict__ xr, float* __restrict__ xi) {
    int idx = blockIdx.x * 256 + threadIdx.x;   // B*32*24*12
    int ky = idx % 12;
    int t  = idx / 12;
    const float* Gr = ws + OFF_GR + (size_t)ky * 64;
    const float* Gi = ws + OFF_GI + (size_t)ky * 64;
    const float* tr = t1r + (size_t)t * 64;
    const float* ti = t1i + (size_t)t * 64;
    float ar = 0.f, ai = 0.f;
#pragma unroll 16
    for (int y = 0; y < 64; y++) {
        float a = tr[y], b = ti[y], c = Gr[y], d = Gi[y];
        ar += a * c - b * d;
        ai += a * d + b * c;
    }
    xr[idx] = ar; xi[idx] = ai;
}

// ---------------- K5: per-mode complex channel mix (the spectral einsum) ----------------
__global__ void k_spec(const float* __restrict__ xr, const float* __restrict__ xi,
                       const float* __restrict__ w1, const float* __restrict__ w2,
                       float* __restrict__ mr, float* __restrict__ mi) {
    int idx = blockIdx.x * 256 + threadIdx.x;   // B*32*24*12 ; layout (b*32+o)*288 + r*12 + ky
    int ky = idx % 12;
    int t  = idx / 12;
    int r  = t % 24;
    int bo = t / 24;
    int o = bo & 31, b = bo >> 5;
    int kx = (r < 12) ? r : (r - 12);
    const float* wl = (r < 12) ? w1 : w2;       // already offset to layer l
    int kxy = kx * 12 + ky;
    float ar = 0.f, ai = 0.f;
    for (int i = 0; i < 32; i++) {
        size_t xoff = ((size_t)(b * 32 + i) * 24 + r) * 12 + ky;
        float a = xr[xoff], bi_ = xi[xoff];
        const float* wp = wl + ((size_t)(i * 32 + o) * 144 + kxy) * 2;
        float wr_ = wp[0], wi_ = wp[1];
        ar += a * wr_ - bi_ * wi_;
        ai += a * wi_ + bi_ * wr_;
    }
    mr[idx] = ar; mi[idx] = ai;
}

// ---------------- K6: inverse DFT over kx rows -> A(b,o,ky,x) ----------------
__global__ void k_inv1(const float* __restrict__ mr, const float* __restrict__ mi,
                       const float* __restrict__ ws, float* __restrict__ Ar, float* __restrict__ Ai) {
    int idx = blockIdx.x * 256 + threadIdx.x;   // B*32*12*64 ; (bo*12+ky)*64 + x
    int x = idx & 63;
    int t = idx >> 6;
    int ky = t % 12;
    int bo = t / 12;
    float ar = 0.f, ai = 0.f;
    for (int r = 0; r < 24; r++) {
        size_t moff = ((size_t)bo * 24 + r) * 12 + ky;
        float a = mr[moff], b = mi[moff];
        float c = ws[OFF_FR + (size_t)r * 64 + x];   // cos(theta)
        float d = ws[OFF_FI + (size_t)r * 64 + x];   // -sin(theta)
        ar += a * c + b * d;
        ai += b * c - a * d;
    }
    Ar[idx] = ar; Ai[idx] = ai;
}

// ---------------- K7a: inverse DFT over ky (c2r semantics) -> spectral image s ----------------
__global__ void k_inv2(const float* __restrict__ Ar, const float* __restrict__ Ai,
                       const float* __restrict__ ws, float* __restrict__ sp) {
    int idx = blockIdx.x * 256 + threadIdx.x;   // B*32*4096
    int p = idx & 4095;
    int y = p & 63, x = p >> 6;
    int bo = idx >> 12;
    const float* ArP = Ar + (size_t)bo * 12 * 64;
    const float* AiP = Ai + (size_t)bo * 12 * 64;
    float s = ArP[x];                            // ky=0: only real part of DC column survives c2r
#pragma unroll
    for (int ky = 1; ky < 12; ky++) {
        float gr = ws[OFF_GR + (size_t)ky * 64 + y];
        float gi = ws[OFF_GI + (size_t)ky * 64 + y];
        s += 2.0f * (ArP[(size_t)ky * 64 + x] * gr + AiP[(size_t)ky * 64 + x] * gi);
    }
    sp[idx] = s * (1.0f / 4096.0f);
}

// ---------------- K7b: per-pixel 1x1 conv (all 32 outputs) + add spectral + gelu ----------------
template <int DOGELU>
__global__ void k_convg(const float* __restrict__ sp, const float* __restrict__ hin,
                        const float* __restrict__ cwt, const float* __restrict__ cb,
                        float* __restrict__ hout) {
    int pix = blockIdx.x * 256 + threadIdx.x;   // 65536
    int b = pix >> 12, p = pix & 4095;
    const float* hp = hin + (size_t)b * WID * NXY + p;
    float hv[32];
#pragma unroll
    for (int c = 0; c < 32; c++) hv[c] = hp[(size_t)c * NXY];
    const float* spp = sp + (size_t)b * WID * NXY + p;
    float* op = hout + (size_t)b * WID * NXY + p;
    for (int o = 0; o < 32; o++) {
        float acc = cb[o];
        const float* wr = cwt + (size_t)o * 32;
#pragma unroll
        for (int c = 0; c < 32; c++) acc += hv[c] * wr[c];
        float v = acc + spp[(size_t)o * NXY];
        if (DOGELU) v = gelu_fast(v);
        op[(size_t)o * NXY] = v;
    }
}

// ---------------- K8: fused head: fc1(32->128)+gelu+fc2(128->6) per pixel ----------------
__global__ void k_head(const float* __restrict__ h, const float* __restrict__ w1t,
                       const float* __restrict__ b1, const float* __restrict__ w2,
                       const float* __restrict__ b2, float* __restrict__ tau) {
    int pix = blockIdx.x * 256 + threadIdx.x;   // 65536
    int b = pix >> 12, p = pix & 4095;
    const float* hp = h + (size_t)b * WID * NXY + p;
    float hv[32];
#pragma unroll
    for (int c = 0; c < 32; c++) hv[c] = hp[(size_t)c * NXY];
    float acc[6] = {0.f, 0.f, 0.f, 0.f, 0.f, 0.f};
    for (int e = 0; e < 128; e++) {
        float d = b1[e];
        const float* wr = w1t + (size_t)e * 32;
#pragma unroll
        for (int c = 0; c < 32; c++) d += wr[c] * hv[c];
        float g = gelu_fast(d);
        const float* w2r = w2 + (size_t)e * 6;
#pragma unroll
        for (int t = 0; t < 6; t++) acc[t] += g * w2r[t];
    }
    float* tb = tau + (size_t)b * 6 * NXY + p;
#pragma unroll
    for (int t = 0; t < 6; t++) tb[(size_t)t * NXY] = acc[t] + b2[t];
}

// ---------------- K10: NS update ----------------
__global__ void k_ns(const float* __restrict__ v, const float* __restrict__ tau,
                     float* __restrict__ out) {
    int idx = blockIdx.x * 256 + threadIdx.x;   // B*64^3
    int b = idx >> 18;
    int srem = idx & (NVOL - 1);
    int x = srem >> 12, y = (srem >> 6) & 63, z = srem & 63;
    int xp = (x + 1) & 63, xm = (x - 1) & 63;
    int yp = (y + 1) & 63, ym = (y - 1) & 63;
    int zp = (z + 1) & 63, zm = (z - 1) & 63;
    float u[3], gx[3], gy[3], gz[3], lap[3];
    for (int i = 0; i < 3; i++) {
        const float* vb = v + (((size_t)(b * 3 + i)) << 18);
        float c   = vb[(size_t)x  * 4096 + y  * 64 + z];
        float axp = vb[(size_t)xp * 4096 + y  * 64 + z];
        float axm = vb[(size_t)xm * 4096 + y  * 64 + z];
        float ayp = vb[(size_t)x  * 4096 + yp * 64 + z];
        float aym = vb[(size_t)x  * 4096 + ym * 64 + z];
        float azp = vb[(size_t)x  * 4096 + y  * 64 + zp];
        float azm = vb[(size_t)x  * 4096 + y  * 64 + zm];
        u[i] = c;
        gx[i] = (axp - axm) * INV2DX;
        gy[i] = (ayp - aym) * INV2DX;
        gz[i] = (azp - azm) * INV2DX;
        lap[i] = (axp + axm + ayp + aym + azp + azm - 6.0f * c) * INVDX2;
    }
    const float* tb = tau + (size_t)b * 6 * NXY;
    int pxp = xp * 64 + y, pxm = xm * 64 + y, pyp = x * 64 + yp, pym = x * 64 + ym;
    float d0 = (tb[0 * NXY + pxp] - tb[0 * NXY + pxm]) * INV2DX +
               (tb[3 * NXY + pyp] - tb[3 * NXY + pym]) * INV2DX;
    float d1 = (tb[3 * NXY + pxp] - tb[3 * NXY + pxm]) * INV2DX +
               (tb[1 * NXY + pyp] - tb[1 * NXY + pym]) * INV2DX;
    float d2 = (tb[4 * NXY + pxp] - tb[4 * NXY + pxm]) * INV2DX +
               (tb[5 * NXY + pyp] - tb[5 * NXY + pym]) * INV2DX;
    float conv0 = u[0] * gx[0] + u[1] * gx[1] + u[2] * gx[2];
    float conv1 = u[0] * gy[0] + u[1] * gy[1] + u[2] * gy[2];
    float conv2 = u[0] * gz[0] + u[1] * gz[1] + u[2] * gz[2];
    size_t so = ((size_t)b * 3) * NVOL + (size_t)srem;
    out[so]            = u[0] + DT_c * (-conv0 + NU_c * lap[0] + d0);
    out[so + NVOL]     = u[1] + DT_c * (-conv1 + NU_c * lap[1] + d1);
    out[so + 2 * NVOL] = u[2] + DT_c * (-conv2 + NU_c * lap[2] + d2);
}

extern "C" void kernel_launch(void* const* d_in, const int* in_sizes, int n_in,
                              void* d_out, int out_size, void* d_ws, size_t ws_size,
                              hipStream_t stream) {
    const float* vel   = (const float*)d_in[0];
    const float* fc0w  = (const float*)d_in[1];
    const float* fc0b  = (const float*)d_in[2];
    const float* sw1   = (const float*)d_in[3];
    const float* sw2   = (const float*)d_in[4];
    const float* convw = (const float*)d_in[5];
    const float* convb = (const float*)d_in[6];
    const float* fc1w  = (const float*)d_in[7];
    const float* fc1b  = (const float*)d_in[8];
    const float* fc2w  = (const float*)d_in[9];
    const float* fc2b  = (const float*)d_in[10];
    float* ws  = (float*)d_ws;
    float* out = (float*)d_out;

    k_twiddle<<<6, 256, 0, stream>>>(ws);
    k_prep<<<34, 256, 0, stream>>>(fc1w, convw, fc0w, ws);
    k_closure<<<256, 256, 0, stream>>>(vel, ws);
    k_fc0<<<256, 256, 0, stream>>>(ws + OFF_CL, ws + OFF_W0T, fc0b, ws + OFF_HA);

    float* hcur  = ws + OFF_HA;
    float* hnext = ws + OFF_HB;
    for (int l = 0; l < 4; l++) {
        const float* wl1 = sw1 + (size_t)l * WID * WID * MM * MM * 2;
        const float* wl2 = sw2 + (size_t)l * WID * WID * MM * MM * 2;
        const float* cwl = ws + OFF_CWT + (size_t)l * WID * WID;
        const float* cbl = convb + (size_t)l * WID;
        k_fwd1<<<3072, 256, 0, stream>>>(hcur, ws, ws + OFF_T1R, ws + OFF_T1I);
        k_fwd2<<<576, 256, 0, stream>>>(ws + OFF_T1R, ws + OFF_T1I, ws, ws + OFF_XR, ws + OFF_XI);
        k_spec<<<576, 256, 0, stream>>>(ws + OFF_XR, ws + OFF_XI, wl1, wl2, ws + OFF_MR, ws + OFF_MI);
        k_inv1<<<1536, 256, 0, stream>>>(ws + OFF_MR, ws + OFF_MI, ws, ws + OFF_AR, ws + OFF_AI);
        k_inv2<<<8192, 256, 0, stream>>>(ws + OFF_AR, ws + OFF_AI, ws, ws + OFF_SP);
        if (l < 3)
            k_convg<1><<<256, 256, 0, stream>>>(ws + OFF_SP, hcur, cwl, cbl, hnext);
        else
            k_convg<0><<<256, 256, 0, stream>>>(ws + OFF_SP, hcur, cwl, cbl, hnext);
        float* tmp = hcur; hcur = hnext; hnext = tmp;
    }

    k_head<<<256, 256, 0, stream>>>(hcur, ws + OFF_W1T, fc1b, fc2w, fc2b, ws + OFF_TAU);
    k_ns<<<16384, 256, 0, stream>>>(vel, ws + OFF_TAU, out);
}

// Round 3
// 393.018 us; speedup vs baseline: 1.0819x; 1.0683x over previous
//
#include <hip/hip_runtime.h>
#include <math.h>

// ---------------- problem constants ----------------
#define NRES 64
#define NXY  4096      // 64*64
#define NVOL 262144    // 64^3
#define BB   16
#define WID  32
#define MM   12
#define R24  24

constexpr double DX_d   = 2.0 * 3.14159265358979323846 / 64.0;
constexpr float  INV2DX = (float)(1.0 / (2.0 * DX_d));
constexpr float  INVDX2 = (float)(1.0 / (DX_d * DX_d));
constexpr float  DT_c   = 0.001f;
constexpr float  NU_c   = 0.002f;

// ---------------- workspace layout (float offsets) ----------------
constexpr size_t OFF_FR  = 0;                                  // 24*64 fwd row twiddles (e^{-i})
constexpr size_t OFF_FI  = OFF_FR + (size_t)R24 * NRES;
constexpr size_t OFF_GR  = OFF_FI + (size_t)R24 * NRES;        // 12*64 col twiddles (e^{-i})
constexpr size_t OFF_GI  = OFF_GR + (size_t)MM * NRES;
constexpr size_t OFF_CL  = OFF_GI + (size_t)MM * NRES;         // closure_in (B,10,64,64)
constexpr size_t OFF_HA  = OFF_CL + (size_t)BB * 10 * NXY;     // h buffer A (B,32,64,64)
constexpr size_t OFF_HB  = OFF_HA + (size_t)BB * WID * NXY;    // h buffer B
constexpr size_t OFF_T1R = OFF_HB + (size_t)BB * WID * NXY;    // (B,32,24,64)
constexpr size_t OFF_T1I = OFF_T1R + (size_t)BB * WID * R24 * NRES;
constexpr size_t OFF_XR  = OFF_T1I + (size_t)BB * WID * R24 * NRES;  // (B,32,24,12)
constexpr size_t OFF_XI  = OFF_XR + (size_t)BB * WID * R24 * MM;
constexpr size_t OFF_MR  = OFF_XI + (size_t)BB * WID * R24 * MM;
constexpr size_t OFF_MI  = OFF_MR + (size_t)BB * WID * R24 * MM;
constexpr size_t OFF_AR  = OFF_MI + (size_t)BB * WID * R24 * MM;     // (B,32,12,64)
constexpr size_t OFF_AI  = OFF_AR + (size_t)BB * WID * MM * NRES;
constexpr size_t OFF_H1  = OFF_AI + (size_t)BB * WID * MM * NRES;    // region reused below
constexpr size_t OFF_TAU = OFF_H1 + (size_t)BB * 128 * NXY;          // (B,6,64,64)

// reuse the (now unneeded) H1 region: spectral image + transposed weights
constexpr size_t OFF_SP  = OFF_H1;                                   // (B,32,64,64)
constexpr size_t OFF_W1T = OFF_H1 + (size_t)BB * WID * NXY;          // 128x32
constexpr size_t OFF_CWT = OFF_W1T + 4096;                           // 4 layers x 32o x 32c
constexpr size_t OFF_W0T = OFF_CWT + 4096;                           // 32d x 10c

__device__ __forceinline__ float gelu_fast(float x) {
    float z = 0.79788456080286535588f * (x + 0.044715f * x * x * x);
    float e = __expf(2.0f * z);
    float t = 1.0f - 2.0f / (e + 1.0f);
    return 0.5f * x * (1.0f + t);
}

// ---------------- K0: twiddle tables ----------------
__global__ void k_twiddle(float* __restrict__ ws) {
    int idx = blockIdx.x * 256 + threadIdx.x;
    if (idx < R24 * NRES) {
        int r = idx / NRES, x = idx % NRES;
        int kx = (r < MM) ? r : (r + 40);   // rows 0..11 and 52..63
        double ang = -2.0 * 3.14159265358979323846 * (double)(kx * x) / 64.0;
        ws[OFF_FR + idx] = (float)cos(ang);
        ws[OFF_FI + idx] = (float)sin(ang);
    }
    if (idx < MM * NRES) {
        int ky = idx / NRES, y = idx % NRES;
        double ang = -2.0 * 3.14159265358979323846 * (double)(ky * y) / 64.0;
        ws[OFF_GR + idx] = (float)cos(ang);
        ws[OFF_GI + idx] = (float)sin(ang);
    }
}

// ---------------- K0b: transpose weights so per-output rows are contiguous (enables s_load) ----
__global__ void k_prep(const float* __restrict__ fc1w, const float* __restrict__ convw,
                       const float* __restrict__ fc0w, float* __restrict__ ws) {
    int i = blockIdx.x * 256 + threadIdx.x;
    if (i < 4096) {                       // fc1_w (32,128) -> W1T[e][c]
        int c = i >> 7, e = i & 127;
        ws[OFF_W1T + (size_t)e * 32 + c] = fc1w[i];
    } else if (i < 8192) {                // conv_w (4,32,32) -> CWT[l][o][c]
        int j = i - 4096;
        int l = j >> 10, r = j & 1023;
        int c = r >> 5, o = r & 31;
        ws[OFF_CWT + (size_t)l * 1024 + o * 32 + c] = convw[j];
    } else if (i < 8512) {                // fc0_w (10,32) -> W0T[d][c]
        int j = i - 8192;
        int c = j >> 5, d = j & 31;
        ws[OFF_W0T + (size_t)d * 10 + c] = fc0w[j];
    }
}

// ---------------- K1: closure input (B,10,64,64) from mid-plane gradients ----------------
__global__ void k_closure(const float* __restrict__ v, float* __restrict__ ws) {
    int idx = blockIdx.x * 256 + threadIdx.x;   // 65536 = B*4096
    int b = idx >> 12, p = idx & 4095;
    int x = p >> 6, z = p & 63;
    int xp = (x + 1) & 63, xm = (x - 1) & 63;
    float g[3][3];
    for (int i = 0; i < 3; i++) {
        const float* vb = v + (((size_t)(b * 3 + i)) << 18);
        float u   = vb[(size_t)x  * 4096 + 32 * 64 + z];
        float uxp = vb[(size_t)xp * 4096 + 32 * 64 + z];
        float uxm = vb[(size_t)xm * 4096 + 32 * 64 + z];
        float uyp = vb[(size_t)x  * 4096 + 33 * 64 + z];
        float uym = vb[(size_t)x  * 4096 + 31 * 64 + z];
        g[i][0] = (uxp - uxm) * INV2DX;
        g[i][1] = (uyp - uym) * INV2DX;
        g[i][2] = 0.1f * u;
    }
    float ss = 0.0f;
    for (int i = 0; i < 3; i++)
        for (int j = 0; j < 3; j++) {
            float s = 0.5f * (g[i][j] + g[j][i]);
            ss += s * s;
        }
    float smag = sqrtf(2.0f * ss);
    float* cl = ws + OFF_CL + (size_t)b * 10 * NXY;
    for (int i = 0; i < 3; i++)
        for (int j = 0; j < 3; j++)
            cl[(size_t)(i * 3 + j) * NXY + p] = g[i][j];
    cl[(size_t)9 * NXY + p] = smag;
}

// ---------------- K2: fc0 lift 10 -> 32 (wave-split over outputs) ----------------
__global__ void k_fc0(const float* __restrict__ cl, const float* __restrict__ w0t,
                      const float* __restrict__ bias, float* __restrict__ h) {
    int tid = threadIdx.x;
    int wid = tid >> 6, lane = tid & 63;
    int pix = blockIdx.x * 64 + lane;           // grid = 1024 blocks
    int b = pix >> 12, p = pix & 4095;
    const float* c0 = cl + (size_t)b * 10 * NXY + p;
    float cv[10];
#pragma unroll
    for (int c = 0; c < 10; c++) cv[c] = c0[(size_t)c * NXY];
    float* hp = h + (size_t)b * WID * NXY + p;
#pragma unroll
    for (int j = 0; j < 8; j++) {
        int d = wid * 8 + j;                    // wave-uniform -> scalar weight loads
        const float* wr = w0t + (size_t)d * 10;
        float a0 = 0.f, a1 = 0.f;
#pragma unroll
        for (int c = 0; c < 10; c += 2) { a0 += cv[c] * wr[c]; a1 += cv[c + 1] * wr[c + 1]; }
        hp[(size_t)d * NXY] = bias[d] + a0 + a1;
    }
}

// ---------------- K3: forward DFT over x (rows), 24 truncated modes ----------------
__global__ void k_fwd1(const float* __restrict__ h, const float* __restrict__ ws,
                       float* __restrict__ t1r, float* __restrict__ t1i) {
    int idx = blockIdx.x * 256 + threadIdx.x;   // B*32*24*64
    int y = idx & 63;
    int t = idx >> 6;          // bc*24 + r
    int r = t % 24;
    int bc = t / 24;
    const float* Fr = ws + OFF_FR + (size_t)r * 64;
    const float* Fi = ws + OFF_FI + (size_t)r * 64;
    const float* hp = h + (size_t)bc * NXY + y;
    float ar = 0.f, ai = 0.f;
#pragma unroll 16
    for (int x = 0; x < 64; x++) {
        float hv = hp[(size_t)x * 64];
        ar += hv * Fr[x];
        ai += hv * Fi[x];
    }
    t1r[idx] = ar; t1i[idx] = ai;
}

// ---------------- K4: forward DFT over y (cols), 12 modes ----------------
__global__ void k_fwd2(const float* __restrict__ t1r, const float* __restrict__ t1i,
                       const float* __restrict__ ws, float* __restrict__ xr, float* __restrict__ xi) {
    int idx = blockIdx.x * 256 + threadIdx.x;   // B*32*24*12
    int ky = idx % 12;
    int t  = idx / 12;
    const float* Gr = ws + OFF_GR + (size_t)ky * 64;
    const float* Gi = ws + OFF_GI + (size_t)ky * 64;
    const float* tr = t1r + (size_t)t * 64;
    const float* ti = t1i + (size_t)t * 64;
    float ar = 0.f, ai = 0.f;
#pragma unroll 16
    for (int y = 0; y < 64; y++) {
        float a = tr[y], b = ti[y], c = Gr[y], d = Gi[y];
        ar += a * c - b * d;
        ai += a * d + b * c;
    }
    xr[idx] = ar; xi[idx] = ai;
}

// ---------------- K5: per-mode complex channel mix (the spectral einsum) ----------------
__global__ void k_spec(const float* __restrict__ xr, const float* __restrict__ xi,
                       const float* __restrict__ w1, const float* __restrict__ w2,
                       float* __restrict__ mr, float* __restrict__ mi) {
    int idx = blockIdx.x * 256 + threadIdx.x;   // B*32*24*12 ; layout (b*32+o)*288 + r*12 + ky
    int ky = idx % 12;
    int t  = idx / 12;
    int r  = t % 24;
    int bo = t / 24;
    int o = bo & 31, b = bo >> 5;
    int kx = (r < 12) ? r : (r - 12);
    const float* wl = (r < 12) ? w1 : w2;       // already offset to layer l
    int kxy = kx * 12 + ky;
    float ar = 0.f, ai = 0.f;
    for (int i = 0; i < 32; i++) {
        size_t xoff = ((size_t)(b * 32 + i) * 24 + r) * 12 + ky;
        float a = xr[xoff], bi_ = xi[xoff];
        const float* wp = wl + ((size_t)(i * 32 + o) * 144 + kxy) * 2;
        float wr_ = wp[0], wi_ = wp[1];
        ar += a * wr_ - bi_ * wi_;
        ai += a * wi_ + bi_ * wr_;
    }
    mr[idx] = ar; mi[idx] = ai;
}

// ---------------- K6: inverse DFT over kx rows -> A(b,o,ky,x) ----------------
__global__ void k_inv1(const float* __restrict__ mr, const float* __restrict__ mi,
                       const float* __restrict__ ws, float* __restrict__ Ar, float* __restrict__ Ai) {
    int idx = blockIdx.x * 256 + threadIdx.x;   // B*32*12*64 ; (bo*12+ky)*64 + x
    int x = idx & 63;
    int t = idx >> 6;
    int ky = t % 12;
    int bo = t / 12;
    float ar = 0.f, ai = 0.f;
    for (int r = 0; r < 24; r++) {
        size_t moff = ((size_t)bo * 24 + r) * 12 + ky;
        float a = mr[moff], b = mi[moff];
        float c = ws[OFF_FR + (size_t)r * 64 + x];   // cos(theta)
        float d = ws[OFF_FI + (size_t)r * 64 + x];   // -sin(theta)
        ar += a * c + b * d;
        ai += b * c - a * d;
    }
    Ar[idx] = ar; Ai[idx] = ai;
}

// ---------------- K7a: inverse DFT over ky (c2r semantics) -> spectral image s ----------------
__global__ void k_inv2(const float* __restrict__ Ar, const float* __restrict__ Ai,
                       const float* __restrict__ ws, float* __restrict__ sp) {
    int idx = blockIdx.x * 256 + threadIdx.x;   // B*32*4096
    int p = idx & 4095;
    int y = p & 63, x = p >> 6;
    int bo = idx >> 12;
    const float* ArP = Ar + (size_t)bo * 12 * 64;
    const float* AiP = Ai + (size_t)bo * 12 * 64;
    float s = ArP[x];                            // ky=0: only real part of DC column survives c2r
#pragma unroll
    for (int ky = 1; ky < 12; ky++) {
        float gr = ws[OFF_GR + (size_t)ky * 64 + y];
        float gi = ws[OFF_GI + (size_t)ky * 64 + y];
        s += 2.0f * (ArP[(size_t)ky * 64 + x] * gr + AiP[(size_t)ky * 64 + x] * gi);
    }
    sp[idx] = s * (1.0f / 4096.0f);
}

// ---------------- K7b: 1x1 conv, wave-split over outputs (8 per wave) ----------------
template <int DOGELU>
__global__ void k_convg(const float* __restrict__ sp, const float* __restrict__ hin,
                        const float* __restrict__ cwt, const float* __restrict__ cb,
                        float* __restrict__ hout) {
    int tid = threadIdx.x;
    int wid = tid >> 6, lane = tid & 63;
    int pix = blockIdx.x * 64 + lane;           // grid = 1024 blocks
    int b = pix >> 12, p = pix & 4095;
    const float* hp = hin + (size_t)b * WID * NXY + p;
    float hv[32];
#pragma unroll
    for (int c = 0; c < 32; c++) hv[c] = hp[(size_t)c * NXY];
    const float* spp = sp + (size_t)b * WID * NXY + p;
    float* op = hout + (size_t)b * WID * NXY + p;
#pragma unroll
    for (int j = 0; j < 8; j++) {
        int o = wid * 8 + j;                    // wave-uniform -> scalar weight loads
        const float* wr = cwt + (size_t)o * 32;
        float a0 = 0.f, a1 = 0.f, a2 = 0.f, a3 = 0.f;
#pragma unroll
        for (int c = 0; c < 32; c += 4) {
            a0 += hv[c]     * wr[c];
            a1 += hv[c + 1] * wr[c + 1];
            a2 += hv[c + 2] * wr[c + 2];
            a3 += hv[c + 3] * wr[c + 3];
        }
        float v = cb[o] + (a0 + a1) + (a2 + a3) + spp[(size_t)o * NXY];
        if (DOGELU) v = gelu_fast(v);
        op[(size_t)o * NXY] = v;
    }
}

// ---------------- K8: fused head, wave-split over e (32 per wave) + LDS reduce ----------------
__global__ void k_head(const float* __restrict__ h, const float* __restrict__ w1t,
                       const float* __restrict__ b1, const float* __restrict__ w2,
                       const float* __restrict__ b2, float* __restrict__ tau) {
    __shared__ float red[4][6][64];
    int tid = threadIdx.x;
    int wid = tid >> 6, lane = tid & 63;
    int pix = blockIdx.x * 64 + lane;           // grid = 1024 blocks
    int b = pix >> 12, p = pix & 4095;
    const float* hp = h + (size_t)b * WID * NXY + p;
    float hv[32];
#pragma unroll
    for (int c = 0; c < 32; c++) hv[c] = hp[(size_t)c * NXY];
    float acc[6] = {0.f, 0.f, 0.f, 0.f, 0.f, 0.f};
    for (int j = 0; j < 32; j++) {
        int e = wid * 32 + j;                   // wave-uniform -> scalar weight loads
        const float* wr = w1t + (size_t)e * 32;
        float d0 = 0.f, d1 = 0.f, d2 = 0.f, d3 = 0.f;
#pragma unroll
        for (int c = 0; c < 32; c += 4) {
            d0 += wr[c]     * hv[c];
            d1 += wr[c + 1] * hv[c + 1];
            d2 += wr[c + 2] * hv[c + 2];
            d3 += wr[c + 3] * hv[c + 3];
        }
        float d = b1[e] + (d0 + d1) + (d2 + d3);
        float g = gelu_fast(d);
        const float* w2r = w2 + (size_t)e * 6;
#pragma unroll
        for (int t = 0; t < 6; t++) acc[t] += g * w2r[t];
    }
#pragma unroll
    for (int t = 0; t < 6; t++) red[wid][t][lane] = acc[t];
    __syncthreads();
    if (wid == 0) {
        float* tb = tau + (size_t)b * 6 * NXY + p;
#pragma unroll
        for (int t = 0; t < 6; t++)
            tb[(size_t)t * NXY] = red[0][t][lane] + red[1][t][lane] +
                                  red[2][t][lane] + red[3][t][lane] + b2[t];
    }
}

// ---------------- K10: NS update ----------------
__global__ void k_ns(const float* __restrict__ v, const float* __restrict__ tau,
                     float* __restrict__ out) {
    int idx = blockIdx.x * 256 + threadIdx.x;   // B*64^3
    int b = idx >> 18;
    int srem = idx & (NVOL - 1);
    int x = srem >> 12, y = (srem >> 6) & 63, z = srem & 63;
    int xp = (x + 1) & 63, xm = (x - 1) & 63;
    int yp = (y + 1) & 63, ym = (y - 1) & 63;
    int zp = (z + 1) & 63, zm = (z - 1) & 63;
    float u[3], gx[3], gy[3], gz[3], lap[3];
    for (int i = 0; i < 3; i++) {
        const float* vb = v + (((size_t)(b * 3 + i)) << 18);
        float c   = vb[(size_t)x  * 4096 + y  * 64 + z];
        float axp = vb[(size_t)xp * 4096 + y  * 64 + z];
        float axm = vb[(size_t)xm * 4096 + y  * 64 + z];
        float ayp = vb[(size_t)x  * 4096 + yp * 64 + z];
        float aym = vb[(size_t)x  * 4096 + ym * 64 + z];
        float azp = vb[(size_t)x  * 4096 + y  * 64 + zp];
        float azm = vb[(size_t)x  * 4096 + y  * 64 + zm];
        u[i] = c;
        gx[i] = (axp - axm) * INV2DX;
        gy[i] = (ayp - aym) * INV2DX;
        gz[i] = (azp - azm) * INV2DX;
        lap[i] = (axp + axm + ayp + aym + azp + azm - 6.0f * c) * INVDX2;
    }
    const float* tb = tau + (size_t)b * 6 * NXY;
    int pxp = xp * 64 + y, pxm = xm * 64 + y, pyp = x * 64 + yp, pym = x * 64 + ym;
    float d0 = (tb[0 * NXY + pxp] - tb[0 * NXY + pxm]) * INV2DX +
               (tb[3 * NXY + pyp] - tb[3 * NXY + pym]) * INV2DX;
    float d1 = (tb[3 * NXY + pxp] - tb[3 * NXY + pxm]) * INV2DX +
               (tb[1 * NXY + pyp] - tb[1 * NXY + pym]) * INV2DX;
    float d2 = (tb[4 * NXY + pxp] - tb[4 * NXY + pxm]) * INV2DX +
               (tb[5 * NXY + pyp] - tb[5 * NXY + pym]) * INV2DX;
    float conv0 = u[0] * gx[0] + u[1] * gx[1] + u[2] * gx[2];
    float conv1 = u[0] * gy[0] + u[1] * gy[1] + u[2] * gy[2];
    float conv2 = u[0] * gz[0] + u[1] * gz[1] + u[2] * gz[2];
    size_t so = ((size_t)b * 3) * NVOL + (size_t)srem;
    out[so]            = u[0] + DT_c * (-conv0 + NU_c * lap[0] + d0);
    out[so + NVOL]     = u[1] + DT_c * (-conv1 + NU_c * lap[1] + d1);
    out[so + 2 * NVOL] = u[2] + DT_c * (-conv2 + NU_c * lap[2] + d2);
}

extern "C" void kernel_launch(void* const* d_in, const int* in_sizes, int n_in,
                              void* d_out, int out_size, void* d_ws, size_t ws_size,
                              hipStream_t stream) {
    const float* vel   = (const float*)d_in[0];
    const float* fc0w  = (const float*)d_in[1];
    const float* fc0b  = (const float*)d_in[2];
    const float* sw1   = (const float*)d_in[3];
    const float* sw2   = (const float*)d_in[4];
    const float* convw = (const float*)d_in[5];
    const float* convb = (const float*)d_in[6];
    const float* fc1w  = (const float*)d_in[7];
    const float* fc1b  = (const float*)d_in[8];
    const float* fc2w  = (const float*)d_in[9];
    const float* fc2b  = (const float*)d_in[10];
    float* ws  = (float*)d_ws;
    float* out = (float*)d_out;

    k_twiddle<<<6, 256, 0, stream>>>(ws);
    k_prep<<<34, 256, 0, stream>>>(fc1w, convw, fc0w, ws);
    k_closure<<<256, 256, 0, stream>>>(vel, ws);
    k_fc0<<<1024, 256, 0, stream>>>(ws + OFF_CL, ws + OFF_W0T, fc0b, ws + OFF_HA);

    float* hcur  = ws + OFF_HA;
    float* hnext = ws + OFF_HB;
    for (int l = 0; l < 4; l++) {
        const float* wl1 = sw1 + (size_t)l * WID * WID * MM * MM * 2;
        const float* wl2 = sw2 + (size_t)l * WID * WID * MM * MM * 2;
        const float* cwl = ws + OFF_CWT + (size_t)l * WID * WID;
        const float* cbl = convb + (size_t)l * WID;
        k_fwd1<<<3072, 256, 0, stream>>>(hcur, ws, ws + OFF_T1R, ws + OFF_T1I);
        k_fwd2<<<576, 256, 0, stream>>>(ws + OFF_T1R, ws + OFF_T1I, ws, ws + OFF_XR, ws + OFF_XI);
        k_spec<<<576, 256, 0, stream>>>(ws + OFF_XR, ws + OFF_XI, wl1, wl2, ws + OFF_MR, ws + OFF_MI);
        k_inv1<<<1536, 256, 0, stream>>>(ws + OFF_MR, ws + OFF_MI, ws, ws + OFF_AR, ws + OFF_AI);
        k_inv2<<<8192, 256, 0, stream>>>(ws + OFF_AR, ws + OFF_AI, ws, ws + OFF_SP);
        if (l < 3)
            k_convg<1><<<1024, 256, 0, stream>>>(ws + OFF_SP, hcur, cwl, cbl, hnext);
        else
            k_convg<0><<<1024, 256, 0, stream>>>(ws + OFF_SP, hcur, cwl, cbl, hnext);
        float* tmp = hcur; hcur = hnext; hnext = tmp;
    }

    k_head<<<1024, 256, 0, stream>>>(hcur, ws + OFF_W1T, fc1b, fc2w, fc2b, ws + OFF_TAU);
    k_ns<<<16384, 256, 0, stream>>>(vel, ws + OFF_TAU, out);
}

// Round 4
// 377.368 us; speedup vs baseline: 1.1268x; 1.0415x over previous
//
#include <hip/hip_runtime.h>
#include <math.h>

// ---------------- problem constants ----------------
#define NRES 64
#define NXY  4096      // 64*64
#define NVOL 262144    // 64^3
#define BB   16
#define WID  32
#define MM   12
#define R24  24

constexpr double DX_d   = 2.0 * 3.14159265358979323846 / 64.0;
constexpr float  INV2DX = (float)(1.0 / (2.0 * DX_d));
constexpr float  INVDX2 = (float)(1.0 / (DX_d * DX_d));
constexpr float  DT_c   = 0.001f;
constexpr float  NU_c   = 0.002f;

// ---------------- workspace layout (float offsets) ----------------
constexpr size_t OFF_FR  = 0;                                  // 24*64 fwd row twiddles (e^{-i})
constexpr size_t OFF_FI  = OFF_FR + (size_t)R24 * NRES;
constexpr size_t OFF_GR  = OFF_FI + (size_t)R24 * NRES;        // 12*64 col twiddles (e^{-i})
constexpr size_t OFF_GI  = OFF_GR + (size_t)MM * NRES;
constexpr size_t OFF_CL  = OFF_GI + (size_t)MM * NRES;         // closure_in (B,10,64,64)
constexpr size_t OFF_HA  = OFF_CL + (size_t)BB * 10 * NXY;     // h buffer A (B,32,64,64)
constexpr size_t OFF_HB  = OFF_HA + (size_t)BB * WID * NXY;    // h buffer B
constexpr size_t OFF_T1R = OFF_HB + (size_t)BB * WID * NXY;    // (B,32,24,64); reused as PT later
constexpr size_t OFF_T1I = OFF_T1R + (size_t)BB * WID * R24 * NRES;
constexpr size_t OFF_XR  = OFF_T1I + (size_t)BB * WID * R24 * NRES;  // (B,32,24,12)
constexpr size_t OFF_XI  = OFF_XR + (size_t)BB * WID * R24 * MM;
constexpr size_t OFF_MR  = OFF_XI + (size_t)BB * WID * R24 * MM;
constexpr size_t OFF_MI  = OFF_MR + (size_t)BB * WID * R24 * MM;
constexpr size_t OFF_AR  = OFF_MI + (size_t)BB * WID * R24 * MM;     // (B,32,12,64)
constexpr size_t OFF_AI  = OFF_AR + (size_t)BB * WID * MM * NRES;
constexpr size_t OFF_H1  = OFF_AI + (size_t)BB * WID * MM * NRES;    // region reused below
constexpr size_t OFF_TAU = OFF_H1 + (size_t)BB * 128 * NXY;          // (B,6,64,64)
// transposed twiddles [x][24] for k_fwd1
constexpr size_t OFF_FRT = OFF_TAU + (size_t)BB * 6 * NXY;
constexpr size_t OFF_FIT = OFF_FRT + (size_t)NRES * R24;

// reuse the (now unneeded) H1 region: spectral image + transposed weights
constexpr size_t OFF_SP  = OFF_H1;                                   // (B,32,64,64)
constexpr size_t OFF_W1T = OFF_H1 + (size_t)BB * WID * NXY;          // 128x32
constexpr size_t OFF_CWT = OFF_W1T + 4096;                           // 4 layers x 32o x 32c
constexpr size_t OFF_W0T = OFF_CWT + 4096;                           // 32d x 10c
// head partials PT[4][B][6][4096] reuse T1 region (exactly 1572864 floats)
constexpr size_t OFF_PT  = OFF_T1R;
constexpr size_t PT_STRIDE = (size_t)BB * 6 * NXY;                   // 393216

__device__ __forceinline__ float gelu_fast(float x) {
    float z = 0.79788456080286535588f * (x + 0.044715f * x * x * x);
    float e = __expf(2.0f * z);
    float t = 1.0f - 2.0f / (e + 1.0f);
    return 0.5f * x * (1.0f + t);
}

// ---------------- K0: twiddle tables + weight transposes (merged setup) ----------------
__global__ void k_setup(const float* __restrict__ fc1w, const float* __restrict__ convw,
                        const float* __restrict__ fc0w, float* __restrict__ ws) {
    int idx = blockIdx.x * 256 + threadIdx.x;   // 34 blocks = 8704 threads
    if (idx < R24 * NRES) {
        int r = idx / NRES, x = idx % NRES;
        int kx = (r < MM) ? r : (r + 40);       // rows 0..11 and 52..63
        double ang = -2.0 * 3.14159265358979323846 * (double)(kx * x) / 64.0;
        float cr = (float)cos(ang), ci = (float)sin(ang);
        ws[OFF_FR + idx] = cr;
        ws[OFF_FI + idx] = ci;
        ws[OFF_FRT + (size_t)x * R24 + r] = cr;
        ws[OFF_FIT + (size_t)x * R24 + r] = ci;
    }
    if (idx < MM * NRES) {
        int ky = idx / NRES, y = idx % NRES;
        double ang = -2.0 * 3.14159265358979323846 * (double)(ky * y) / 64.0;
        ws[OFF_GR + idx] = (float)cos(ang);
        ws[OFF_GI + idx] = (float)sin(ang);
    }
    if (idx < 4096) {                           // fc1_w (32,128) -> W1T[e][c]
        int c = idx >> 7, e = idx & 127;
        ws[OFF_W1T + (size_t)e * 32 + c] = fc1w[idx];
    } else if (idx < 8192) {                    // conv_w (4,32,32) -> CWT[l][o][c]
        int j = idx - 4096;
        int l = j >> 10, r = j & 1023;
        int c = r >> 5, o = r & 31;
        ws[OFF_CWT + (size_t)l * 1024 + o * 32 + c] = convw[j];
    } else if (idx < 8512) {                    // fc0_w (10,32) -> W0T[d][c]
        int j = idx - 8192;
        int c = j >> 5, d = j & 31;
        ws[OFF_W0T + (size_t)d * 10 + c] = fc0w[j];
    }
}

// ---------------- K1: closure input (B,10,64,64) from mid-plane gradients ----------------
__global__ void k_closure(const float* __restrict__ v, float* __restrict__ ws) {
    int idx = blockIdx.x * 256 + threadIdx.x;   // 65536 = B*4096
    int b = idx >> 12, p = idx & 4095;
    int x = p >> 6, z = p & 63;
    int xp = (x + 1) & 63, xm = (x - 1) & 63;
    float g[3][3];
    for (int i = 0; i < 3; i++) {
        const float* vb = v + (((size_t)(b * 3 + i)) << 18);
        float u   = vb[(size_t)x  * 4096 + 32 * 64 + z];
        float uxp = vb[(size_t)xp * 4096 + 32 * 64 + z];
        float uxm = vb[(size_t)xm * 4096 + 32 * 64 + z];
        float uyp = vb[(size_t)x  * 4096 + 33 * 64 + z];
        float uym = vb[(size_t)x  * 4096 + 31 * 64 + z];
        g[i][0] = (uxp - uxm) * INV2DX;
        g[i][1] = (uyp - uym) * INV2DX;
        g[i][2] = 0.1f * u;
    }
    float ss = 0.0f;
    for (int i = 0; i < 3; i++)
        for (int j = 0; j < 3; j++) {
            float s = 0.5f * (g[i][j] + g[j][i]);
            ss += s * s;
        }
    float smag = sqrtf(2.0f * ss);
    float* cl = ws + OFF_CL + (size_t)b * 10 * NXY;
    for (int i = 0; i < 3; i++)
        for (int j = 0; j < 3; j++)
            cl[(size_t)(i * 3 + j) * NXY + p] = g[i][j];
    cl[(size_t)9 * NXY + p] = smag;
}

// ---------------- K2: fc0 lift 10 -> 32 (wave-split over outputs) ----------------
__global__ void k_fc0(const float* __restrict__ cl, const float* __restrict__ w0t,
                      const float* __restrict__ bias, float* __restrict__ h) {
    int tid = threadIdx.x;
    int wid = tid >> 6, lane = tid & 63;
    int pix = blockIdx.x * 64 + lane;           // grid = 1024 blocks
    int b = pix >> 12, p = pix & 4095;
    const float* c0 = cl + (size_t)b * 10 * NXY + p;
    float cv[10];
#pragma unroll
    for (int c = 0; c < 10; c++) cv[c] = c0[(size_t)c * NXY];
    float* hp = h + (size_t)b * WID * NXY + p;
#pragma unroll
    for (int j = 0; j < 8; j++) {
        int d = wid * 8 + j;                    // wave-uniform -> scalar weight loads
        const float* wr = w0t + (size_t)d * 10;
        float a0 = 0.f, a1 = 0.f;
#pragma unroll
        for (int c = 0; c < 10; c += 2) { a0 += cv[c] * wr[c]; a1 += cv[c + 1] * wr[c + 1]; }
        hp[(size_t)d * NXY] = bias[d] + a0 + a1;
    }
}

// ---------------- K3: forward DFT over x, 4 kx-modes per thread ----------------
__global__ void k_fwd1(const float* __restrict__ h, const float* __restrict__ ws,
                       float* __restrict__ t1r, float* __restrict__ t1i) {
    int idx = blockIdx.x * 256 + threadIdx.x;   // B*32*6*64 = 196608 -> 768 blocks
    int y = idx & 63;
    int t = idx >> 6;          // bc*6 + rg
    int rg = t % 6;
    int bc = t / 6;
    const float* FRT = ws + OFF_FRT + rg * 4;   // [x][24] transposed tables
    const float* FIT = ws + OFF_FIT + rg * 4;
    const float* hp = h + (size_t)bc * NXY + y;
    float ar0 = 0.f, ai0 = 0.f, ar1 = 0.f, ai1 = 0.f;
    float ar2 = 0.f, ai2 = 0.f, ar3 = 0.f, ai3 = 0.f;
#pragma unroll 8
    for (int x = 0; x < 64; x++) {
        float hv = hp[(size_t)x * 64];
        const float* fr = FRT + (size_t)x * R24;
        const float* fi = FIT + (size_t)x * R24;
        ar0 += hv * fr[0]; ai0 += hv * fi[0];
        ar1 += hv * fr[1]; ai1 += hv * fi[1];
        ar2 += hv * fr[2]; ai2 += hv * fi[2];
        ar3 += hv * fr[3]; ai3 += hv * fi[3];
    }
    size_t base = ((size_t)bc * 24 + rg * 4) * 64 + y;
    t1r[base]       = ar0; t1i[base]       = ai0;
    t1r[base + 64]  = ar1; t1i[base + 64]  = ai1;
    t1r[base + 128] = ar2; t1i[base + 128] = ai2;
    t1r[base + 192] = ar3; t1i[base + 192] = ai3;
}

// ---------------- K4: forward DFT over y (cols), 12 modes ----------------
__global__ void k_fwd2(const float* __restrict__ t1r, const float* __restrict__ t1i,
                       const float* __restrict__ ws, float* __restrict__ xr, float* __restrict__ xi) {
    int idx = blockIdx.x * 256 + threadIdx.x;   // B*32*24*12
    int ky = idx % 12;
    int t  = idx / 12;
    const float* Gr = ws + OFF_GR + (size_t)ky * 64;
    const float* Gi = ws + OFF_GI + (size_t)ky * 64;
    const float* tr = t1r + (size_t)t * 64;
    const float* ti = t1i + (size_t)t * 64;
    float ar = 0.f, ai = 0.f;
#pragma unroll 16
    for (int y = 0; y < 64; y++) {
        float a = tr[y], b = ti[y], c = Gr[y], d = Gi[y];
        ar += a * c - b * d;
        ai += a * d + b * c;
    }
    xr[idx] = ar; xi[idx] = ai;
}

// ---------------- K5: per-mode complex channel mix (the spectral einsum) ----------------
__global__ void k_spec(const float* __restrict__ xr, const float* __restrict__ xi,
                       const float* __restrict__ w1, const float* __restrict__ w2,
                       float* __restrict__ mr, float* __restrict__ mi) {
    int idx = blockIdx.x * 256 + threadIdx.x;   // B*32*24*12 ; layout (b*32+o)*288 + r*12 + ky
    int ky = idx % 12;
    int t  = idx / 12;
    int r  = t % 24;
    int bo = t / 24;
    int o = bo & 31, b = bo >> 5;
    int kx = (r < 12) ? r : (r - 12);
    const float* wl = (r < 12) ? w1 : w2;       // already offset to layer l
    int kxy = kx * 12 + ky;
    float ar = 0.f, ai = 0.f;
    for (int i = 0; i < 32; i++) {
        size_t xoff = ((size_t)(b * 32 + i) * 24 + r) * 12 + ky;
        float a = xr[xoff], bi_ = xi[xoff];
        const float* wp = wl + ((size_t)(i * 32 + o) * 144 + kxy) * 2;
        float wr_ = wp[0], wi_ = wp[1];
        ar += a * wr_ - bi_ * wi_;
        ai += a * wi_ + bi_ * wr_;
    }
    mr[idx] = ar; mi[idx] = ai;
}

// ---------------- K6: inverse DFT over kx rows -> A(b,o,ky,x) ----------------
__global__ void k_inv1(const float* __restrict__ mr, const float* __restrict__ mi,
                       const float* __restrict__ ws, float* __restrict__ Ar, float* __restrict__ Ai) {
    int idx = blockIdx.x * 256 + threadIdx.x;   // B*32*12*64 ; (bo*12+ky)*64 + x
    int x = idx & 63;
    int t = idx >> 6;
    int ky = t % 12;
    int bo = t / 12;
    float ar = 0.f, ai = 0.f;
    for (int r = 0; r < 24; r++) {
        size_t moff = ((size_t)bo * 24 + r) * 12 + ky;
        float a = mr[moff], b = mi[moff];
        float c = ws[OFF_FR + (size_t)r * 64 + x];   // cos(theta)
        float d = ws[OFF_FI + (size_t)r * 64 + x];   // -sin(theta)
        ar += a * c + b * d;
        ai += b * c - a * d;
    }
    Ar[idx] = ar; Ai[idx] = ai;
}

// ---------------- K7a: inverse DFT over ky (c2r semantics) -> spectral image s ----------------
__global__ void k_inv2(const float* __restrict__ Ar, const float* __restrict__ Ai,
                       const float* __restrict__ ws, float* __restrict__ sp) {
    int idx = blockIdx.x * 256 + threadIdx.x;   // B*32*4096
    int p = idx & 4095;
    int y = p & 63, x = p >> 6;
    int bo = idx >> 12;
    const float* ArP = Ar + (size_t)bo * 12 * 64;
    const float* AiP = Ai + (size_t)bo * 12 * 64;
    float s = ArP[x];                            // ky=0: only real part of DC column survives c2r
#pragma unroll
    for (int ky = 1; ky < 12; ky++) {
        float gr = ws[OFF_GR + (size_t)ky * 64 + y];
        float gi = ws[OFF_GI + (size_t)ky * 64 + y];
        s += 2.0f * (ArP[(size_t)ky * 64 + x] * gr + AiP[(size_t)ky * 64 + x] * gi);
    }
    sp[idx] = s * (1.0f / 4096.0f);
}

// ---------------- K7b: 1x1 conv, o-split across 2 blocks, 4 o per wave ----------------
template <int DOGELU>
__global__ void k_convg(const float* __restrict__ sp, const float* __restrict__ hin,
                        const float* __restrict__ cwt, const float* __restrict__ cb,
                        float* __restrict__ hout) {
    int tid = threadIdx.x;
    int wid = tid >> 6, lane = tid & 63;
    int blk = blockIdx.x;                       // grid = 2048 blocks
    int osec = blk & 1;
    int pix = (blk >> 1) * 64 + lane;
    int b = pix >> 12, p = pix & 4095;
    const float* hp = hin + (size_t)b * WID * NXY + p;
    float hv[32];
#pragma unroll
    for (int c = 0; c < 32; c++) hv[c] = hp[(size_t)c * NXY];
    const float* spp = sp + (size_t)b * WID * NXY + p;
    float* op = hout + (size_t)b * WID * NXY + p;
#pragma unroll
    for (int j = 0; j < 4; j++) {
        int o = osec * 16 + wid * 4 + j;        // wave-uniform -> scalar weight loads
        const float* wr = cwt + (size_t)o * 32;
        float a0 = 0.f, a1 = 0.f, a2 = 0.f, a3 = 0.f;
#pragma unroll
        for (int c = 0; c < 32; c += 4) {
            a0 += hv[c]     * wr[c];
            a1 += hv[c + 1] * wr[c + 1];
            a2 += hv[c + 2] * wr[c + 2];
            a3 += hv[c + 3] * wr[c + 3];
        }
        float v = cb[o] + (a0 + a1) + (a2 + a3) + spp[(size_t)o * NXY];
        if (DOGELU) v = gelu_fast(v);
        op[(size_t)o * NXY] = v;
    }
}

// ---------------- K8: fused head, e-split across 4 blocks, 8 e per wave ----------------
__global__ void k_head(const float* __restrict__ h, const float* __restrict__ w1t,
                       const float* __restrict__ b1, const float* __restrict__ w2,
                       float* __restrict__ pt) {
    __shared__ float red[4][6][64];
    int tid = threadIdx.x;
    int wid = tid >> 6, lane = tid & 63;
    int blk = blockIdx.x;                       // grid = 4096 blocks
    int esec = blk & 3;
    int pix = (blk >> 2) * 64 + lane;
    int b = pix >> 12, p = pix & 4095;
    const float* hp = h + (size_t)b * WID * NXY + p;
    float hv[32];
#pragma unroll
    for (int c = 0; c < 32; c++) hv[c] = hp[(size_t)c * NXY];
    float acc[6] = {0.f, 0.f, 0.f, 0.f, 0.f, 0.f};
#pragma unroll
    for (int j = 0; j < 8; j++) {
        int e = esec * 32 + wid * 8 + j;        // wave-uniform -> scalar weight loads
        const float* wr = w1t + (size_t)e * 32;
        float d0 = 0.f, d1 = 0.f, d2 = 0.f, d3 = 0.f;
#pragma unroll
        for (int c = 0; c < 32; c += 4) {
            d0 += wr[c]     * hv[c];
            d1 += wr[c + 1] * hv[c + 1];
            d2 += wr[c + 2] * hv[c + 2];
            d3 += wr[c + 3] * hv[c + 3];
        }
        float d = b1[e] + (d0 + d1) + (d2 + d3);
        float g = gelu_fast(d);
        const float* w2r = w2 + (size_t)e * 6;
#pragma unroll
        for (int t = 0; t < 6; t++) acc[t] += g * w2r[t];
    }
#pragma unroll
    for (int t = 0; t < 6; t++) red[wid][t][lane] = acc[t];
    __syncthreads();
    if (wid == 0) {
        float* pb = pt + (size_t)esec * PT_STRIDE + (size_t)b * 6 * NXY + p;
#pragma unroll
        for (int t = 0; t < 6; t++)
            pb[(size_t)t * NXY] = red[0][t][lane] + red[1][t][lane] +
                                  red[2][t][lane] + red[3][t][lane];
    }
}

// ---------------- K8b: reduce 4 head partials + bias -> tau ----------------
__global__ void k_tred(const float* __restrict__ pt, const float* __restrict__ b2,
                       float* __restrict__ tau) {
    int idx = blockIdx.x * 256 + threadIdx.x;   // 393216 -> 1536 blocks
    int t = (idx >> 12) % 6;
    float s = pt[idx] + pt[idx + PT_STRIDE] + pt[idx + 2 * PT_STRIDE] + pt[idx + 3 * PT_STRIDE];
    tau[idx] = s + b2[t];
}

// ---------------- K10: NS update ----------------
__global__ void k_ns(const float* __restrict__ v, const float* __restrict__ tau,
                     float* __restrict__ out) {
    int idx = blockIdx.x * 256 + threadIdx.x;   // B*64^3
    int b = idx >> 18;
    int srem = idx & (NVOL - 1);
    int x = srem >> 12, y = (srem >> 6) & 63, z = srem & 63;
    int xp = (x + 1) & 63, xm = (x - 1) & 63;
    int yp = (y + 1) & 63, ym = (y - 1) & 63;
    int zp = (z + 1) & 63, zm = (z - 1) & 63;
    float u[3], gx[3], gy[3], gz[3], lap[3];
    for (int i = 0; i < 3; i++) {
        const float* vb = v + (((size_t)(b * 3 + i)) << 18);
        float c   = vb[(size_t)x  * 4096 + y  * 64 + z];
        float axp = vb[(size_t)xp * 4096 + y  * 64 + z];
        float axm = vb[(size_t)xm * 4096 + y  * 64 + z];
        float ayp = vb[(size_t)x  * 4096 + yp * 64 + z];
        float aym = vb[(size_t)x  * 4096 + ym * 64 + z];
        float azp = vb[(size_t)x  * 4096 + y  * 64 + zp];
        float azm = vb[(size_t)x  * 4096 + y  * 64 + zm];
        u[i] = c;
        gx[i] = (axp - axm) * INV2DX;
        gy[i] = (ayp - aym) * INV2DX;
        gz[i] = (azp - azm) * INV2DX;
        lap[i] = (axp + axm + ayp + aym + azp + azm - 6.0f * c) * INVDX2;
    }
    const float* tb = tau + (size_t)b * 6 * NXY;
    int pxp = xp * 64 + y, pxm = xm * 64 + y, pyp = x * 64 + yp, pym = x * 64 + ym;
    float d0 = (tb[0 * NXY + pxp] - tb[0 * NXY + pxm]) * INV2DX +
               (tb[3 * NXY + pyp] - tb[3 * NXY + pym]) * INV2DX;
    float d1 = (tb[3 * NXY + pxp] - tb[3 * NXY + pxm]) * INV2DX +
               (tb[1 * NXY + pyp] - tb[1 * NXY + pym]) * INV2DX;
    float d2 = (tb[4 * NXY + pxp] - tb[4 * NXY + pxm]) * INV2DX +
               (tb[5 * NXY + pyp] - tb[5 * NXY + pym]) * INV2DX;
    float conv0 = u[0] * gx[0] + u[1] * gx[1] + u[2] * gx[2];
    float conv1 = u[0] * gy[0] + u[1] * gy[1] + u[2] * gy[2];
    float conv2 = u[0] * gz[0] + u[1] * gz[1] + u[2] * gz[2];
    size_t so = ((size_t)b * 3) * NVOL + (size_t)srem;
    out[so]            = u[0] + DT_c * (-conv0 + NU_c * lap[0] + d0);
    out[so + NVOL]     = u[1] + DT_c * (-conv1 + NU_c * lap[1] + d1);
    out[so + 2 * NVOL] = u[2] + DT_c * (-conv2 + NU_c * lap[2] + d2);
}

extern "C" void kernel_launch(void* const* d_in, const int* in_sizes, int n_in,
                              void* d_out, int out_size, void* d_ws, size_t ws_size,
                              hipStream_t stream) {
    const float* vel   = (const float*)d_in[0];
    const float* fc0w  = (const float*)d_in[1];
    const float* fc0b  = (const float*)d_in[2];
    const float* sw1   = (const float*)d_in[3];
    const float* sw2   = (const float*)d_in[4];
    const float* convw = (const float*)d_in[5];
    const float* convb = (const float*)d_in[6];
    const float* fc1w  = (const float*)d_in[7];
    const float* fc1b  = (const float*)d_in[8];
    const float* fc2w  = (const float*)d_in[9];
    const float* fc2b  = (const float*)d_in[10];
    float* ws  = (float*)d_ws;
    float* out = (float*)d_out;

    k_setup<<<34, 256, 0, stream>>>(fc1w, convw, fc0w, ws);
    k_closure<<<256, 256, 0, stream>>>(vel, ws);
    k_fc0<<<1024, 256, 0, stream>>>(ws + OFF_CL, ws + OFF_W0T, fc0b, ws + OFF_HA);

    float* hcur  = ws + OFF_HA;
    float* hnext = ws + OFF_HB;
    for (int l = 0; l < 4; l++) {
        const float* wl1 = sw1 + (size_t)l * WID * WID * MM * MM * 2;
        const float* wl2 = sw2 + (size_t)l * WID * WID * MM * MM * 2;
        const float* cwl = ws + OFF_CWT + (size_t)l * WID * WID;
        const float* cbl = convb + (size_t)l * WID;
        k_fwd1<<<768, 256, 0, stream>>>(hcur, ws, ws + OFF_T1R, ws + OFF_T1I);
        k_fwd2<<<576, 256, 0, stream>>>(ws + OFF_T1R, ws + OFF_T1I, ws, ws + OFF_XR, ws + OFF_XI);
        k_spec<<<576, 256, 0, stream>>>(ws + OFF_XR, ws + OFF_XI, wl1, wl2, ws + OFF_MR, ws + OFF_MI);
        k_inv1<<<1536, 256, 0, stream>>>(ws + OFF_MR, ws + OFF_MI, ws, ws + OFF_AR, ws + OFF_AI);
        k_inv2<<<8192, 256, 0, stream>>>(ws + OFF_AR, ws + OFF_AI, ws, ws + OFF_SP);
        if (l < 3)
            k_convg<1><<<2048, 256, 0, stream>>>(ws + OFF_SP, hcur, cwl, cbl, hnext);
        else
            k_convg<0><<<2048, 256, 0, stream>>>(ws + OFF_SP, hcur, cwl, cbl, hnext);
        float* tmp = hcur; hcur = hnext; hnext = tmp;
    }

    k_head<<<4096, 256, 0, stream>>>(hcur, ws + OFF_W1T, fc1b, fc2w, ws + OFF_PT);
    k_tred<<<1536, 256, 0, stream>>>(ws + OFF_PT, fc2b, ws + OFF_TAU);
    k_ns<<<16384, 256, 0, stream>>>(vel, ws + OFF_TAU, out);
}

// Round 6
// 260.996 us; speedup vs baseline: 1.6292x; 1.4459x over previous
//
#include <hip/hip_runtime.h>
#include <math.h>

// ---------------- problem constants ----------------
#define NRES 64
#define NXY  4096      // 64*64
#define NVOL 262144    // 64^3
#define BB   16
#define WID  32
#define MM   12
#define R24  24

constexpr double DX_d   = 2.0 * 3.14159265358979323846 / 64.0;
constexpr float  INV2DX = (float)(1.0 / (2.0 * DX_d));
constexpr float  INVDX2 = (float)(1.0 / (DX_d * DX_d));
constexpr float  DT_c   = 0.001f;
constexpr float  NU_c   = 0.002f;

// ---------------- workspace layout (float offsets) ----------------
constexpr size_t OFF_FR  = 0;                                  // 24*64 fwd row twiddles (e^{-i})
constexpr size_t OFF_FI  = OFF_FR + (size_t)R24 * NRES;
constexpr size_t OFF_GR  = OFF_FI + (size_t)R24 * NRES;        // 12*64 col twiddles (e^{-i})
constexpr size_t OFF_GI  = OFF_GR + (size_t)MM * NRES;
constexpr size_t OFF_CL  = OFF_GI + (size_t)MM * NRES;         // closure_in (B,10,64,64)
constexpr size_t OFF_HA  = OFF_CL + (size_t)BB * 10 * NXY;     // h buffer A (B,32,64,64)
constexpr size_t OFF_HB  = OFF_HA + (size_t)BB * WID * NXY;    // h buffer B
constexpr size_t OFF_T1R = OFF_HB + (size_t)BB * WID * NXY;    // reused as PT (head partials)
constexpr size_t OFF_T1I = OFF_T1R + (size_t)BB * WID * R24 * NRES;
constexpr size_t OFF_XR  = OFF_T1I + (size_t)BB * WID * R24 * NRES;  // (B,32,24,12)
constexpr size_t OFF_XI  = OFF_XR + (size_t)BB * WID * R24 * MM;
constexpr size_t OFF_MR  = OFF_XI + (size_t)BB * WID * R24 * MM;
constexpr size_t OFF_MI  = OFF_MR + (size_t)BB * WID * R24 * MM;
constexpr size_t OFF_AR  = OFF_MI + (size_t)BB * WID * R24 * MM;     // (unused now)
constexpr size_t OFF_AI  = OFF_AR + (size_t)BB * WID * MM * NRES;
constexpr size_t OFF_H1  = OFF_AI + (size_t)BB * WID * MM * NRES;    // region reused below
constexpr size_t OFF_TAU = OFF_H1 + (size_t)BB * 128 * NXY;          // (B,6,64,64)
// transposed twiddles [x][24] for k_fwd
constexpr size_t OFF_FRT = OFF_TAU + (size_t)BB * 6 * NXY;
constexpr size_t OFF_FIT = OFF_FRT + (size_t)NRES * R24;

// reuse the H1 region: spectral image + transposed weights
constexpr size_t OFF_SP  = OFF_H1;                                   // (B,32,64,64)
constexpr size_t OFF_W1T = OFF_H1 + (size_t)BB * WID * NXY;          // 128x32
constexpr size_t OFF_CWT = OFF_W1T + 4096;                           // 4 layers x 32o x 32c
constexpr size_t OFF_W0T = OFF_CWT + 4096;                           // 32d x 10c
// head partials PT[2][B][6][4096] reuse T1 region
constexpr size_t OFF_PT  = OFF_T1R;
constexpr size_t PT_STRIDE = (size_t)BB * 6 * NXY;                   // 393216

__device__ __forceinline__ float gelu_fast(float x) {
    float z = 0.79788456080286535588f * (x + 0.044715f * x * x * x);
    float e = __expf(2.0f * z);
    float t = 1.0f - 2.0f / (e + 1.0f);
    return 0.5f * x * (1.0f + t);
}

// ---------------- K0: twiddle tables + weight transposes (merged setup) ----------------
__global__ void k_setup(const float* __restrict__ fc1w, const float* __restrict__ convw,
                        const float* __restrict__ fc0w, float* __restrict__ ws) {
    int idx = blockIdx.x * 256 + threadIdx.x;   // 34 blocks
    if (idx < R24 * NRES) {
        int r = idx / NRES, x = idx % NRES;
        int kx = (r < MM) ? r : (r + 40);       // rows 0..11 and 52..63
        double ang = -2.0 * 3.14159265358979323846 * (double)(kx * x) / 64.0;
        float cr = (float)cos(ang), ci = (float)sin(ang);
        ws[OFF_FR + idx] = cr;
        ws[OFF_FI + idx] = ci;
        ws[OFF_FRT + (size_t)x * R24 + r] = cr;
        ws[OFF_FIT + (size_t)x * R24 + r] = ci;
    }
    if (idx < MM * NRES) {
        int ky = idx / NRES, y = idx % NRES;
        double ang = -2.0 * 3.14159265358979323846 * (double)(ky * y) / 64.0;
        ws[OFF_GR + idx] = (float)cos(ang);
        ws[OFF_GI + idx] = (float)sin(ang);
    }
    if (idx < 4096) {                           // fc1_w (32,128) -> W1T[e][c]
        int c = idx >> 7, e = idx & 127;
        ws[OFF_W1T + (size_t)e * 32 + c] = fc1w[idx];
    } else if (idx < 8192) {                    // conv_w (4,32,32) -> CWT[l][o][c]
        int j = idx - 4096;
        int l = j >> 10, r = j & 1023;
        int c = r >> 5, o = r & 31;
        ws[OFF_CWT + (size_t)l * 1024 + o * 32 + c] = convw[j];
    } else if (idx < 8512) {                    // fc0_w (10,32) -> W0T[d][c]
        int j = idx - 8192;
        int c = j >> 5, d = j & 31;
        ws[OFF_W0T + (size_t)d * 10 + c] = fc0w[j];
    }
}

// ---------------- K1: closure input (B,10,64,64) from mid-plane gradients ----------------
__global__ void k_closure(const float* __restrict__ v, float* __restrict__ ws) {
    int idx = blockIdx.x * 256 + threadIdx.x;   // 65536
    int b = idx >> 12, p = idx & 4095;
    int x = p >> 6, z = p & 63;
    int xp = (x + 1) & 63, xm = (x - 1) & 63;
    float g[3][3];
    for (int i = 0; i < 3; i++) {
        const float* vb = v + (((size_t)(b * 3 + i)) << 18);
        float u   = vb[(size_t)x  * 4096 + 32 * 64 + z];
        float uxp = vb[(size_t)xp * 4096 + 32 * 64 + z];
        float uxm = vb[(size_t)xm * 4096 + 32 * 64 + z];
        float uyp = vb[(size_t)x  * 4096 + 33 * 64 + z];
        float uym = vb[(size_t)x  * 4096 + 31 * 64 + z];
        g[i][0] = (uxp - uxm) * INV2DX;
        g[i][1] = (uyp - uym) * INV2DX;
        g[i][2] = 0.1f * u;
    }
    float ss = 0.0f;
    for (int i = 0; i < 3; i++)
        for (int j = 0; j < 3; j++) {
            float s = 0.5f * (g[i][j] + g[j][i]);
            ss += s * s;
        }
    float smag = sqrtf(2.0f * ss);
    float* cl = ws + OFF_CL + (size_t)b * 10 * NXY;
    for (int i = 0; i < 3; i++)
        for (int j = 0; j < 3; j++)
            cl[(size_t)(i * 3 + j) * NXY + p] = g[i][j];
    cl[(size_t)9 * NXY + p] = smag;
}

// ---------------- K2: fc0 lift 10 -> 32 (LDS-staged weights) ----------------
__global__ void k_fc0(const float* __restrict__ cl, const float* __restrict__ w0t,
                      const float* __restrict__ bias, float* __restrict__ h) {
    __shared__ __align__(16) float sw[32 * 12];
    __shared__ float sb[32];
    int tid = threadIdx.x;
    for (int i = tid; i < 320; i += 256) {      // FIX: strided (320 > 256 threads)
        int d = i / 10, c = i % 10;
        sw[d * 12 + c] = w0t[i];
    }
    if (tid < 32) sb[tid] = bias[tid];
    __syncthreads();
    int wid = tid >> 6, lane = tid & 63;
    int pix = blockIdx.x * 64 + lane;           // grid = 1024 blocks
    int b = pix >> 12, p = pix & 4095;
    const float* c0 = cl + (size_t)b * 10 * NXY + p;
    float cv[10];
#pragma unroll
    for (int c = 0; c < 10; c++) cv[c] = c0[(size_t)c * NXY];
    float* hp = h + (size_t)b * WID * NXY + p;
#pragma unroll
    for (int j = 0; j < 8; j++) {
        int d = wid * 8 + j;
        const float4* wr = (const float4*)&sw[d * 12];
        float4 w0 = wr[0], w1 = wr[1];
        float a0 = w0.x * cv[0] + w0.y * cv[1] + w0.z * cv[2] + w0.w * cv[3];
        float a1 = w1.x * cv[4] + w1.y * cv[5] + w1.z * cv[6] + w1.w * cv[7];
        float a2 = sw[d * 12 + 8] * cv[8] + sw[d * 12 + 9] * cv[9];
        hp[(size_t)d * NXY] = sb[d] + a0 + a1 + a2;
    }
}

// ---------------- K3: fused forward DFT (x then y), one block per (b,c) ----------------
__global__ void k_fwd(const float* __restrict__ h, const float* __restrict__ ws,
                      float* __restrict__ xr, float* __restrict__ xi) {
    __shared__ __align__(16) float sh[4096];
    __shared__ float st1r[24 * 65];
    __shared__ float st1i[24 * 65];
    int tid = threadIdx.x;
    int bc = blockIdx.x;                        // grid = 512
    // stage h image
    const float4* hp4 = (const float4*)(h + (size_t)bc * NXY);
    float4* sh4 = (float4*)sh;
#pragma unroll
    for (int i = 0; i < 4; i++) sh4[tid + 256 * i] = hp4[tid + 256 * i];
    __syncthreads();
    // phase 1: DFT over x -> t1[r][y]
    const float* FRT = ws + OFF_FRT;
    const float* FIT = ws + OFF_FIT;
#pragma unroll
    for (int it = 0; it < 6; it++) {
        int point = it * 256 + tid;
        int y = point & 63;
        int rr = __builtin_amdgcn_readfirstlane(point >> 6);
        float ar = 0.f, ai = 0.f;
#pragma unroll 16
        for (int x = 0; x < 64; x++) {
            float hv = sh[x * 64 + y];
            ar += hv * FRT[x * R24 + rr];
            ai += hv * FIT[x * R24 + rr];
        }
        st1r[rr * 65 + y] = ar;
        st1i[rr * 65 + y] = ai;
    }
    __syncthreads();
    // phase 2: DFT over y -> X[r][ky]
    const float* GR = ws + OFF_GR;
    const float* GI = ws + OFF_GI;
#pragma unroll
    for (int it = 0; it < 2; it++) {
        int point = it * 256 + tid;
        if (point < 288) {
            int r = point / 12, ky = point - r * 12;
            const float* Gr = GR + (size_t)ky * 64;
            const float* Gi = GI + (size_t)ky * 64;
            float ar = 0.f, ai = 0.f;
#pragma unroll 16
            for (int y = 0; y < 64; y++) {
                float a = st1r[r * 65 + y], b = st1i[r * 65 + y];
                float c = Gr[y], d = Gi[y];
                ar += a * c - b * d;
                ai += a * d + b * c;
            }
            xr[(size_t)bc * 288 + point] = ar;
            xi[(size_t)bc * 288 + point] = ai;
        }
    }
}

// ---------------- K5: per-mode complex channel mix (the spectral einsum) ----------------
__global__ void k_spec(const float* __restrict__ xr, const float* __restrict__ xi,
                       const float* __restrict__ w1, const float* __restrict__ w2,
                       float* __restrict__ mr, float* __restrict__ mi) {
    int idx = blockIdx.x * 256 + threadIdx.x;   // B*32*24*12 ; layout (b*32+o)*288 + r*12 + ky
    int ky = idx % 12;
    int t  = idx / 12;
    int r  = t % 24;
    int bo = t / 24;
    int o = bo & 31, b = bo >> 5;
    int kx = (r < 12) ? r : (r - 12);
    const float* wl = (r < 12) ? w1 : w2;       // already offset to layer l
    int kxy = kx * 12 + ky;
    float ar = 0.f, ai = 0.f;
    for (int i = 0; i < 32; i++) {
        size_t xoff = ((size_t)(b * 32 + i) * 24 + r) * 12 + ky;
        float a = xr[xoff], bi_ = xi[xoff];
        const float* wp = wl + ((size_t)(i * 32 + o) * 144 + kxy) * 2;
        float wr_ = wp[0], wi_ = wp[1];
        ar += a * wr_ - bi_ * wi_;
        ai += a * wi_ + bi_ * wr_;
    }
    mr[idx] = ar; mi[idx] = ai;
}

// ---------------- K6: fused inverse DFT (kx then ky, c2r) -> sp ; one block per (b,o) -------
__global__ void k_invf(const float* __restrict__ mr, const float* __restrict__ mi,
                       const float* __restrict__ ws, float* __restrict__ sp) {
    __shared__ float sm_r[288];
    __shared__ float sm_i[288];
    __shared__ float sa_r[12 * 64];
    __shared__ float sa_i[12 * 64];
    int tid = threadIdx.x;
    int bo = blockIdx.x;                        // grid = 512
    for (int i = tid; i < 288; i += 256) {      // FIX: strided (288 > 256 threads)
        sm_r[i] = mr[(size_t)bo * 288 + i];
        sm_i[i] = mi[(size_t)bo * 288 + i];
    }
    __syncthreads();
    const float* FR = ws + OFF_FR;
    const float* FI = ws + OFF_FI;
    // phase 1: A[ky][x] = sum_r M[r][ky] * e^{+i 2pi kx x / 64}
#pragma unroll
    for (int it = 0; it < 3; it++) {
        int point = it * 256 + tid;
        int x = point & 63;
        int ky = __builtin_amdgcn_readfirstlane(point >> 6);
        float ar = 0.f, ai = 0.f;
#pragma unroll 8
        for (int r = 0; r < 24; r++) {
            float a = sm_r[r * 12 + ky], b = sm_i[r * 12 + ky];
            float c = FR[r * 64 + x], d = FI[r * 64 + x];   // cos, -sin
            ar += a * c + b * d;
            ai += b * c - a * d;
        }
        sa_r[ky * 64 + x] = ar;
        sa_i[ky * 64 + x] = ai;
    }
    __syncthreads();
    const float* GR = ws + OFF_GR;
    const float* GI = ws + OFF_GI;
    float* spb = sp + (size_t)bo * NXY;
    // phase 2: c2r over ky
#pragma unroll
    for (int it = 0; it < 16; it++) {
        int px = it * 256 + tid;
        int y = px & 63;
        int x = __builtin_amdgcn_readfirstlane(px >> 6);
        float s = sa_r[x];                      // ky=0: Re only
#pragma unroll
        for (int ky = 1; ky < 12; ky++) {
            float gr = GR[ky * 64 + y];
            float gi = GI[ky * 64 + y];
            s += 2.0f * (sa_r[ky * 64 + x] * gr + sa_i[ky * 64 + x] * gi);
        }
        spb[px] = s * (1.0f / 4096.0f);
    }
}

// ---------------- K7: 1x1 conv (LDS weights), o-split across 2, 4 o per wave ----------------
template <int DOGELU>
__global__ void k_convg(const float* __restrict__ sp, const float* __restrict__ hin,
                        const float* __restrict__ cwt, const float* __restrict__ cb,
                        float* __restrict__ hout) {
    __shared__ __align__(16) float scw[1024];
    __shared__ float scb[32];
    int tid = threadIdx.x;
#pragma unroll
    for (int i = 0; i < 4; i++) scw[tid + 256 * i] = cwt[tid + 256 * i];
    if (tid < 32) scb[tid] = cb[tid];
    __syncthreads();
    int wid = tid >> 6, lane = tid & 63;
    int blk = blockIdx.x;                       // grid = 2048
    int osec = blk & 1;
    int pix = (blk >> 1) * 64 + lane;
    int b = pix >> 12, p = pix & 4095;
    const float* hp = hin + (size_t)b * WID * NXY + p;
    float hv[32];
#pragma unroll
    for (int c = 0; c < 32; c++) hv[c] = hp[(size_t)c * NXY];
    const float* spp = sp + (size_t)b * WID * NXY + p;
    float* op = hout + (size_t)b * WID * NXY + p;
#pragma unroll
    for (int j = 0; j < 4; j++) {
        int o = osec * 16 + wid * 4 + j;
        const float4* wr = (const float4*)&scw[o * 32];
        float a0 = 0.f, a1 = 0.f, a2 = 0.f, a3 = 0.f;
#pragma unroll
        for (int q = 0; q < 8; q += 4) {
            float4 w0 = wr[q], w1 = wr[q + 1], w2 = wr[q + 2], w3 = wr[q + 3];
            a0 += w0.x * hv[q * 4]      + w0.y * hv[q * 4 + 1]  + w0.z * hv[q * 4 + 2]  + w0.w * hv[q * 4 + 3];
            a1 += w1.x * hv[q * 4 + 4]  + w1.y * hv[q * 4 + 5]  + w1.z * hv[q * 4 + 6]  + w1.w * hv[q * 4 + 7];
            a2 += w2.x * hv[q * 4 + 8]  + w2.y * hv[q * 4 + 9]  + w2.z * hv[q * 4 + 10] + w2.w * hv[q * 4 + 11];
            a3 += w3.x * hv[q * 4 + 12] + w3.y * hv[q * 4 + 13] + w3.z * hv[q * 4 + 14] + w3.w * hv[q * 4 + 15];
        }
        float v = scb[o] + (a0 + a1) + (a2 + a3) + spp[(size_t)o * NXY];
        if (DOGELU) v = gelu_fast(v);
        op[(size_t)o * NXY] = v;
    }
}

// ---------------- K8: fused head (LDS weights), e-split across 2, 16 e per wave ----------------
__global__ void k_head(const float* __restrict__ h, const float* __restrict__ w1t,
                       const float* __restrict__ b1, const float* __restrict__ w2,
                       float* __restrict__ pt) {
    __shared__ __align__(16) float sw1[4096];
    __shared__ float sb1[128];
    __shared__ __align__(16) float sw2[128 * 8];
    __shared__ float red[4][6][64];
    int tid = threadIdx.x;
#pragma unroll
    for (int i = 0; i < 16; i++) sw1[tid + 256 * i] = w1t[tid + 256 * i];
    if (tid < 128) sb1[tid] = b1[tid];
    {   // w2 (128x6) -> padded (128x8)
        for (int i = tid; i < 768; i += 256) {
            int e = i / 6, t = i - e * 6;
            sw2[e * 8 + t] = w2[i];
        }
    }
    __syncthreads();
    int wid = tid >> 6, lane = tid & 63;
    int blk = blockIdx.x;                       // grid = 2048
    int esec = blk & 1;
    int pix = (blk >> 1) * 64 + lane;
    int b = pix >> 12, p = pix & 4095;
    const float* hp = h + (size_t)b * WID * NXY + p;
    float hv[32];
#pragma unroll
    for (int c = 0; c < 32; c++) hv[c] = hp[(size_t)c * NXY];
    float acc[6] = {0.f, 0.f, 0.f, 0.f, 0.f, 0.f};
#pragma unroll
    for (int jj = 0; jj < 16; jj++) {
        int e = esec * 64 + wid * 16 + jj;
        const float4* wr = (const float4*)&sw1[e * 32];
        float d0 = 0.f, d1 = 0.f, d2 = 0.f, d3 = 0.f;
#pragma unroll
        for (int q = 0; q < 8; q += 4) {
            float4 w0 = wr[q], w1 = wr[q + 1], w2_ = wr[q + 2], w3 = wr[q + 3];
            d0 += w0.x * hv[q * 4]      + w0.y * hv[q * 4 + 1]  + w0.z * hv[q * 4 + 2]  + w0.w * hv[q * 4 + 3];
            d1 += w1.x * hv[q * 4 + 4]  + w1.y * hv[q * 4 + 5]  + w1.z * hv[q * 4 + 6]  + w1.w * hv[q * 4 + 7];
            d2 += w2_.x * hv[q * 4 + 8] + w2_.y * hv[q * 4 + 9] + w2_.z * hv[q * 4 + 10]+ w2_.w * hv[q * 4 + 11];
            d3 += w3.x * hv[q * 4 + 12] + w3.y * hv[q * 4 + 13] + w3.z * hv[q * 4 + 14] + w3.w * hv[q * 4 + 15];
        }
        float d = sb1[e] + (d0 + d1) + (d2 + d3);
        float g = gelu_fast(d);
        const float4* w2r = (const float4*)&sw2[e * 8];
        float4 wa = w2r[0], wb = w2r[1];
        acc[0] += g * wa.x; acc[1] += g * wa.y; acc[2] += g * wa.z;
        acc[3] += g * wa.w; acc[4] += g * wb.x; acc[5] += g * wb.y;
    }
#pragma unroll
    for (int t = 0; t < 6; t++) red[wid][t][lane] = acc[t];
    __syncthreads();
    if (wid == 0) {
        float* pb = pt + (size_t)esec * PT_STRIDE + (size_t)b * 6 * NXY + p;
#pragma unroll
        for (int t = 0; t < 6; t++)
            pb[(size_t)t * NXY] = red[0][t][lane] + red[1][t][lane] +
                                  red[2][t][lane] + red[3][t][lane];
    }
}

// ---------------- K8b: reduce 2 head partials + bias -> tau ----------------
__global__ void k_tred(const float* __restrict__ pt, const float* __restrict__ b2,
                       float* __restrict__ tau) {
    int idx = blockIdx.x * 256 + threadIdx.x;   // 393216 -> 1536 blocks
    int t = (idx >> 12) % 6;
    tau[idx] = pt[idx] + pt[idx + PT_STRIDE] + b2[t];
}

// ---------------- K10: NS update ----------------
__global__ void k_ns(const float* __restrict__ v, const float* __restrict__ tau,
                     float* __restrict__ out) {
    int idx = blockIdx.x * 256 + threadIdx.x;   // B*64^3
    int b = idx >> 18;
    int srem = idx & (NVOL - 1);
    int x = srem >> 12, y = (srem >> 6) & 63, z = srem & 63;
    int xp = (x + 1) & 63, xm = (x - 1) & 63;
    int yp = (y + 1) & 63, ym = (y - 1) & 63;
    int zp = (z + 1) & 63, zm = (z - 1) & 63;
    float u[3], gx[3], gy[3], gz[3], lap[3];
    for (int i = 0; i < 3; i++) {
        const float* vb = v + (((size_t)(b * 3 + i)) << 18);
        float c   = vb[(size_t)x  * 4096 + y  * 64 + z];
        float axp = vb[(size_t)xp * 4096 + y  * 64 + z];
        float axm = vb[(size_t)xm * 4096 + y  * 64 + z];
        float ayp = vb[(size_t)x  * 4096 + yp * 64 + z];
        float aym = vb[(size_t)x  * 4096 + ym * 64 + z];
        float azp = vb[(size_t)x  * 4096 + y  * 64 + zp];
        float azm = vb[(size_t)x  * 4096 + y  * 64 + zm];
        u[i] = c;
        gx[i] = (axp - axm) * INV2DX;
        gy[i] = (ayp - aym) * INV2DX;
        gz[i] = (azp - azm) * INV2DX;
        lap[i] = (axp + axm + ayp + aym + azp + azm - 6.0f * c) * INVDX2;
    }
    const float* tb = tau + (size_t)b * 6 * NXY;
    int pxp = xp * 64 + y, pxm = xm * 64 + y, pyp = x * 64 + yp, pym = x * 64 + ym;
    float d0 = (tb[0 * NXY + pxp] - tb[0 * NXY + pxm]) * INV2DX +
               (tb[3 * NXY + pyp] - tb[3 * NXY + pym]) * INV2DX;
    float d1 = (tb[3 * NXY + pxp] - tb[3 * NXY + pxm]) * INV2DX +
               (tb[1 * NXY + pyp] - tb[1 * NXY + pym]) * INV2DX;
    float d2 = (tb[4 * NXY + pxp] - tb[4 * NXY + pxm]) * INV2DX +
               (tb[5 * NXY + pyp] - tb[5 * NXY + pym]) * INV2DX;
    float conv0 = u[0] * gx[0] + u[1] * gx[1] + u[2] * gx[2];
    float conv1 = u[0] * gy[0] + u[1] * gy[1] + u[2] * gy[2];
    float conv2 = u[0] * gz[0] + u[1] * gz[1] + u[2] * gz[2];
    size_t so = ((size_t)b * 3) * NVOL + (size_t)srem;
    out[so]            = u[0] + DT_c * (-conv0 + NU_c * lap[0] + d0);
    out[so + NVOL]     = u[1] + DT_c * (-conv1 + NU_c * lap[1] + d1);
    out[so + 2 * NVOL] = u[2] + DT_c * (-conv2 + NU_c * lap[2] + d2);
}

extern "C" void kernel_launch(void* const* d_in, const int* in_sizes, int n_in,
                              void* d_out, int out_size, void* d_ws, size_t ws_size,
                              hipStream_t stream) {
    const float* vel   = (const float*)d_in[0];
    const float* fc0w  = (const float*)d_in[1];
    const float* fc0b  = (const float*)d_in[2];
    const float* sw1   = (const float*)d_in[3];
    const float* sw2   = (const float*)d_in[4];
    const float* convw = (const float*)d_in[5];
    const float* convb = (const float*)d_in[6];
    const float* fc1w  = (const float*)d_in[7];
    const float* fc1b  = (const float*)d_in[8];
    const float* fc2w  = (const float*)d_in[9];
    const float* fc2b  = (const float*)d_in[10];
    float* ws  = (float*)d_ws;
    float* out = (float*)d_out;

    k_setup<<<34, 256, 0, stream>>>(fc1w, convw, fc0w, ws);
    k_closure<<<256, 256, 0, stream>>>(vel, ws);
    k_fc0<<<1024, 256, 0, stream>>>(ws + OFF_CL, ws + OFF_W0T, fc0b, ws + OFF_HA);

    float* hcur  = ws + OFF_HA;
    float* hnext = ws + OFF_HB;
    for (int l = 0; l < 4; l++) {
        const float* wl1 = sw1 + (size_t)l * WID * WID * MM * MM * 2;
        const float* wl2 = sw2 + (size_t)l * WID * WID * MM * MM * 2;
        const float* cwl = ws + OFF_CWT + (size_t)l * WID * WID;
        const float* cbl = convb + (size_t)l * WID;
        k_fwd<<<512, 256, 0, stream>>>(hcur, ws, ws + OFF_XR, ws + OFF_XI);
        k_spec<<<576, 256, 0, stream>>>(ws + OFF_XR, ws + OFF_XI, wl1, wl2, ws + OFF_MR, ws + OFF_MI);
        k_invf<<<512, 256, 0, stream>>>(ws + OFF_MR, ws + OFF_MI, ws, ws + OFF_SP);
        if (l < 3)
            k_convg<1><<<2048, 256, 0, stream>>>(ws + OFF_SP, hcur, cwl, cbl, hnext);
        else
            k_convg<0><<<2048, 256, 0, stream>>>(ws + OFF_SP, hcur, cwl, cbl, hnext);
        float* tmp = hcur; hcur = hnext; hnext = tmp;
    }

    k_head<<<2048, 256, 0, stream>>>(hcur, ws + OFF_W1T, fc1b, fc2w, ws + OFF_PT);
    k_tred<<<1536, 256, 0, stream>>>(ws + OFF_PT, fc2b, ws + OFF_TAU);
    k_ns<<<16384, 256, 0, stream>>>(vel, ws + OFF_TAU, out);
}